// Round 5
// baseline (895.302 us; speedup 1.0000x reference)
//
#include <hip/hip_runtime.h>
#include <math.h>

#define TPB 256
#define TOPK 30
#define NGRAPH 128
#define TKCAP 4096

// ---------------- CSR build ----------------

__global__ void count_edges(const int* __restrict__ src, const int* __restrict__ dst,
                            int* __restrict__ cnt, int E) {
    int e = blockIdx.x * blockDim.x + threadIdx.x;
    if (e >= E) return;
    int s = src[e], d = dst[e];
    if (s != d) atomicAdd(&cnt[d], 1);
}

__global__ void deg_finish(const int* __restrict__ cnt, float* __restrict__ dinv,
                           float* __restrict__ snorm, int n) {
    int i = blockIdx.x * blockDim.x + threadIdx.x;
    if (i >= n) return;
    float deg = (float)cnt[i] + 1.0f;
    dinv[i] = 1.0f / sqrtf(deg);
    snorm[i] = 1.0f / deg;
}

// exclusive scan, 1024 elems per block
__global__ void scan1(const int* __restrict__ cnt, int* __restrict__ outp,
                      int* __restrict__ bsum, int n) {
    __shared__ int ls[256];
    int t = threadIdx.x;
    int base = blockIdx.x * 1024;
    int v[4], ex[4];
    int run = 0;
    #pragma unroll
    for (int j = 0; j < 4; ++j) {
        int i = base + t * 4 + j;
        v[j] = (i < n) ? cnt[i] : 0;
        ex[j] = run;
        run += v[j];
    }
    ls[t] = run;
    __syncthreads();
    for (int o2 = 1; o2 < 256; o2 <<= 1) {
        int xv = 0;
        if (t >= o2) xv = ls[t - o2];
        __syncthreads();
        ls[t] += xv;
        __syncthreads();
    }
    int tbase = ls[t] - run;   // exclusive base for this thread
    #pragma unroll
    for (int j = 0; j < 4; ++j) {
        int i = base + t * 4 + j;
        if (i < n) outp[i] = tbase + ex[j];
    }
    if (t == 255) bsum[blockIdx.x] = ls[255];
}

__global__ void scan2(int* __restrict__ bsum, int nb) {
    __shared__ int ls[256];
    int t = threadIdx.x;
    int v = (t < nb) ? bsum[t] : 0;
    ls[t] = v;
    __syncthreads();
    for (int o2 = 1; o2 < 256; o2 <<= 1) {
        int xv = 0;
        if (t >= o2) xv = ls[t - o2];
        __syncthreads();
        ls[t] += xv;
        __syncthreads();
    }
    if (t < nb) bsum[t] = ls[t] - v;     // exclusive
    if (t == 255) bsum[nb] = ls[255];    // total
}

__global__ void scan3(int* __restrict__ rowptr, const int* __restrict__ bsum, int n, int nb) {
    int i = blockIdx.x * blockDim.x + threadIdx.x;
    if (i < n) rowptr[i] += bsum[i >> 10];
    if (i == 0) rowptr[n] = bsum[nb];
}

// XCD-sliced scatter: block (xcd=b&7, slice=b>>3) streams its edge slice
// (non-temporal, coalesced) and keeps only edges whose dst lies in xcd's
// node range. All stores to a given eprec line then come from one XCD's L2
// (region ~3.2MB < 4MB L2) -> lines fill before eviction, killing the 8x
// write amplification. Correct regardless of actual block->XCD mapping.
__global__ void scatter_edges_xcd(const int* __restrict__ src, const int* __restrict__ dst,
                                  const int* __restrict__ rowptr, int* __restrict__ cursor,
                                  const float* __restrict__ dinv,
                                  int2* __restrict__ eprec, int E, int nper, int nslices) {
    int b = blockIdx.x;
    int xcd = b & 7;
    int s = b >> 3;
    long e0 = (long)s * E / nslices;
    long e1 = (long)(s + 1) * E / nslices;
    int dlo = xcd * nper, dhi = dlo + nper;
    for (long e = e0 + threadIdx.x; e < e1; e += blockDim.x) {
        int d = __builtin_nontemporal_load(dst + e);
        if (d < dlo || d >= dhi) continue;
        int sv = __builtin_nontemporal_load(src + e);
        if (sv == d) continue;
        int p = rowptr[d] + atomicAdd(&cursor[d], 1);
        eprec[p] = make_int2(sv, __float_as_int(dinv[sv] * dinv[d]));
    }
}

// ---------------- GEMMs ----------------

__global__ void mm_128_32(const float* __restrict__ X, const float* __restrict__ W,
                          float* __restrict__ H, int n) {
    __shared__ float Ws[128 * 32];
    __shared__ float xs[8 * 128];
    int t = threadIdx.x;
    for (int i = t; i < 128 * 32; i += 256) Ws[i] = W[i];
    int rbase = blockIdx.x * 8;
    {
        int i = t * 4;  // 0..1020, covers all 1024
        int rr = rbase + (i >> 7);
        float4 v = make_float4(0.f, 0.f, 0.f, 0.f);
        if (rr < n) v = *(const float4*)(X + (long)rbase * 128 + i);
        *(float4*)(xs + i) = v;
    }
    __syncthreads();
    int c = t & 31, r = t >> 5;
    int row = rbase + r;
    if (row >= n) return;
    float acc = 0.f;
    #pragma unroll 16
    for (int k = 0; k < 128; ++k) acc += xs[r * 128 + k] * Ws[k * 32 + c];
    H[(long)row * 32 + c] = acc;
}

__global__ void mm_32_32(const float* __restrict__ X, const float* __restrict__ W,
                         float* __restrict__ H, int n) {
    __shared__ float Ws[32 * 32];
    __shared__ float xs[8 * 32];
    int t = threadIdx.x;
    for (int i = t; i < 32 * 32; i += 256) Ws[i] = W[i];
    int rbase = blockIdx.x * 8;
    {
        int rr = rbase + (t >> 5);
        xs[t] = (rr < n) ? X[(long)rbase * 32 + t] : 0.f;
    }
    __syncthreads();
    int c = t & 31, r = t >> 5;
    int row = rbase + r;
    if (row >= n) return;
    float acc = 0.f;
    #pragma unroll
    for (int k = 0; k < 32; ++k) acc += xs[r * 32 + k] * Ws[k * 32 + c];
    H[(long)row * 32 + c] = acc;
}

__global__ void mm_32_1(const float* __restrict__ X, const float* __restrict__ W,
                        float* __restrict__ H4, int n) {
    int gid = blockIdx.x * blockDim.x + threadIdx.x;
    int node = gid >> 3, l = gid & 7;
    if (node >= n) return;
    float4 v = *(const float4*)(X + (long)node * 32 + l * 4);
    float s = v.x * W[l * 4] + v.y * W[l * 4 + 1] + v.z * W[l * 4 + 2] + v.w * W[l * 4 + 3];
    s += __shfl_xor(s, 1, 64);
    s += __shfl_xor(s, 2, 64);
    s += __shfl_xor(s, 4, 64);
    if (l == 0) H4[node] = s;
}

// ---------------- edge aggregation (gather) ----------------

__global__ void agg32(const float* __restrict__ H, const int2* __restrict__ eprec,
                      const int* __restrict__ rowptr,
                      const float* __restrict__ snorm, const float* __restrict__ bias,
                      float* __restrict__ OUT, int n) {
    int gid = blockIdx.x * blockDim.x + threadIdx.x;
    int node = gid >> 3, l = gid & 7;
    if (node >= n) return;
    int beg = rowptr[node], end = rowptr[node + 1];
    float ax = 0.f, ay = 0.f, az = 0.f, aw = 0.f;
    int e0 = beg;
    // full batches of 8: unrolled, 8 independent gathers in flight
    for (; e0 + 8 <= end; e0 += 8) {
        int2 ed = eprec[e0 + l];       // coalesced: 8 lanes load 8 consecutive edges
        int ss[8]; float ww[8];
        #pragma unroll
        for (int j = 0; j < 8; ++j) {
            ss[j] = __shfl(ed.x, j, 8);
            ww[j] = __shfl(__int_as_float(ed.y), j, 8);
        }
        float4 hv[8];
        #pragma unroll
        for (int j = 0; j < 8; ++j)
            hv[j] = *(const float4*)(H + (long)ss[j] * 32 + l * 4);
        #pragma unroll
        for (int j = 0; j < 8; ++j) {
            ax += hv[j].x * ww[j]; ay += hv[j].y * ww[j];
            az += hv[j].z * ww[j]; aw += hv[j].w * ww[j];
        }
    }
    // tail
    if (e0 < end) {
        int m = end - e0;
        int2 ed = (l < m) ? eprec[e0 + l] : make_int2(0, 0);
        for (int j = 0; j < m; ++j) {
            int s = __shfl(ed.x, j, 8);
            float w = __shfl(__int_as_float(ed.y), j, 8);
            float4 hv = *(const float4*)(H + (long)s * 32 + l * 4);
            ax += hv.x * w; ay += hv.y * w; az += hv.z * w; aw += hv.w * w;
        }
    }
    float sn = snorm[node];
    float4 hv = *(const float4*)(H + (long)node * 32 + l * 4);
    float4 bv = *(const float4*)(bias + l * 4);
    float4 o;
    o.x = tanhf(ax + hv.x * sn + bv.x);
    o.y = tanhf(ay + hv.y * sn + bv.y);
    o.z = tanhf(az + hv.z * sn + bv.z);
    o.w = tanhf(aw + hv.w * sn + bv.w);
    *(float4*)(OUT + (long)node * 32 + l * 4) = o;
}

__global__ void agg1(const float* __restrict__ H4, const int2* __restrict__ eprec,
                     const int* __restrict__ rowptr,
                     const float* __restrict__ snorm, const float* __restrict__ b4,
                     float* __restrict__ X4, int n) {
    int node = blockIdx.x * blockDim.x + threadIdx.x;
    if (node >= n) return;
    int beg = rowptr[node], end = rowptr[node + 1];
    float acc = 0.f;
    for (int e = beg; e < end; ++e) {
        int2 ed = eprec[e];
        acc += H4[ed.x] * __int_as_float(ed.y);
    }
    X4[node] = tanhf(acc + H4[node] * snorm[node] + b4[0]);
}

// ---------------- topk per graph: 1 wave, LDS-staged argmax-with-marking ----------------

__global__ void graph_start(const int* __restrict__ batch, int* __restrict__ gstart,
                            int n, int B) {
    int i = blockIdx.x * blockDim.x + threadIdx.x;
    if (i >= n) return;
    int b = batch[i];
    int bp = (i == 0) ? -1 : batch[i - 1];
    for (int g = bp + 1; g <= b; ++g) gstart[g] = i;
    if (i == n - 1) {
        for (int g = b + 1; g <= B; ++g) gstart[g] = n;
    }
}

__global__ __launch_bounds__(64) void topk_kernel(const float* __restrict__ keyf,
                                                  const int* __restrict__ gstart,
                                                  int* __restrict__ topi) {
    int g = blockIdx.x;
    int t = threadIdx.x;  // 0..63, single wave
    __shared__ float vals[TKCAP];
    __shared__ int selg[TOPK];
    int beg = gstart[g], end = gstart[g + 1];
    int range = end - beg;
    int lim = range < TKCAP ? range : TKCAP;
    for (int i = t; i < lim; i += 64) vals[i] = keyf[beg + i];
    __syncthreads();
    for (int k = 0; k < TOPK; ++k) {
        float best = -INFINITY;
        int bi = 0x7fffffff;
        // LDS region: strict > keeps lowest index within a lane
        for (int i = t; i < lim; i += 64) {
            float v = vals[i];
            if (v > best) { best = v; bi = i; }
        }
        // overflow region from global (never triggered at range<=TKCAP)
        for (int i = TKCAP + t; i < range; i += 64) {
            int gi = beg + i;
            bool taken = false;
            for (int j = 0; j < k; ++j)
                if (selg[j] == gi) { taken = true; break; }
            if (taken) continue;
            float v = keyf[gi];
            if (v > best || (v == best && i < bi)) { best = v; bi = i; }
        }
        // wave argmax reduce, tie -> lower index
        #pragma unroll
        for (int off = 1; off < 64; off <<= 1) {
            float ov = __shfl_xor(best, off, 64);
            int oi = __shfl_xor(bi, off, 64);
            if (ov > best || (ov == best && oi < bi)) { best = ov; bi = oi; }
        }
        if (t == 0) {
            int gl = (bi == 0x7fffffff) ? -1 : beg + bi;
            selg[k] = gl;
            topi[g * TOPK + k] = gl;
            if (bi != 0x7fffffff && bi < TKCAP) vals[bi] = -INFINITY;
        }
        __syncthreads();
    }
}

// ---------------- head: conv5 -> pool -> conv6 -> fc1 -> fc2 -> log_softmax ----------------

__global__ void head_kernel(const float* __restrict__ x1, const float* __restrict__ x2,
                            const float* __restrict__ x3, const float* __restrict__ x4,
                            const int* __restrict__ topi,
                            const float* __restrict__ w5, const float* __restrict__ b5,
                            const float* __restrict__ w6, const float* __restrict__ b6,
                            const float* __restrict__ fw1, const float* __restrict__ fb1,
                            const float* __restrict__ fw2, const float* __restrict__ fb2,
                            float* __restrict__ out) {
    int b = blockIdx.x;
    int t = threadIdx.x;
    __shared__ float feats[TOPK][97];
    __shared__ float c5[16][30];
    __shared__ float p6[16][15];
    __shared__ float z[352];
    __shared__ float hh[128];
    __shared__ float oo[10];

    for (int idx = t; idx < TOPK * 97; idx += 256) {
        int k = idx / 97, j = idx % 97;
        int node = topi[b * TOPK + k];
        float v = 0.f;
        if (node >= 0) {
            if (j < 32) v = x1[(long)node * 32 + j];
            else if (j < 64) v = x2[(long)node * 32 + (j - 32)];
            else if (j < 96) v = x3[(long)node * 32 + (j - 64)];
            else v = x4[node];
        }
        feats[k][j] = v;
    }
    __syncthreads();

    for (int idx = t; idx < 16 * 30; idx += 256) {
        int oc = idx / 30, k = idx % 30;
        float acc = b5[oc];
        for (int j = 0; j < 97; ++j) acc += w5[oc * 97 + j] * feats[k][j];
        c5[oc][k] = fmaxf(acc, 0.f);
    }
    __syncthreads();

    for (int idx = t; idx < 16 * 15; idx += 256) {
        int oc = idx / 15, k = idx % 15;
        p6[oc][k] = fmaxf(c5[oc][2 * k], c5[oc][2 * k + 1]);
    }
    __syncthreads();

    for (int idx = t; idx < 32 * 11; idx += 256) {
        int oc = idx / 11, tt = idx % 11;
        float acc = b6[oc];
        for (int ic = 0; ic < 16; ++ic)
            for (int j = 0; j < 5; ++j)
                acc += w6[(oc * 16 + ic) * 5 + j] * p6[ic][tt + j];
        z[idx] = fmaxf(acc, 0.f);
    }
    __syncthreads();

    if (t < 128) {
        float acc = fb1[t];
        for (int i = 0; i < 352; ++i) acc += z[i] * fw1[i * 128 + t];
        hh[t] = fmaxf(acc, 0.f);
    }
    __syncthreads();

    if (t < 10) {
        float acc = fb2[t];
        for (int j = 0; j < 128; ++j) acc += hh[j] * fw2[j * 10 + t];
        oo[t] = acc;
    }
    __syncthreads();

    if (t < 10) {
        float m = -INFINITY;
        for (int c = 0; c < 10; ++c) m = fmaxf(m, oo[c]);
        float s = 0.f;
        for (int c = 0; c < 10; ++c) s += expf(oo[c] - m);
        out[b * 10 + t] = oo[t] - m - logf(s);
    }
}

// ---------------- launch ----------------

extern "C" void kernel_launch(void* const* d_in, const int* in_sizes, int n_in,
                              void* d_out, int out_size, void* d_ws, size_t ws_size,
                              hipStream_t stream) {
    const float* x     = (const float*)d_in[0];
    const int*   ei    = (const int*)d_in[1];
    const int*   batch = (const int*)d_in[2];
    const float* W1 = (const float*)d_in[3];
    const float* b1 = (const float*)d_in[4];
    const float* W2 = (const float*)d_in[5];
    const float* b2 = (const float*)d_in[6];
    const float* W3 = (const float*)d_in[7];
    const float* b3 = (const float*)d_in[8];
    const float* W4 = (const float*)d_in[9];
    const float* b4 = (const float*)d_in[10];
    const float* w5 = (const float*)d_in[11];
    const float* b5 = (const float*)d_in[12];
    const float* w6 = (const float*)d_in[13];
    const float* b6 = (const float*)d_in[14];
    const float* fw1 = (const float*)d_in[15];
    const float* fb1 = (const float*)d_in[16];
    const float* fw2 = (const float*)d_in[17];
    const float* fb2 = (const float*)d_in[18];

    const int N = in_sizes[0] / 128;
    const int E = in_sizes[1] / 2;
    const int* src = ei;
    const int* dst = ei + E;

    char* w = (char*)d_ws;
    size_t off = 0;
    auto alloc = [&](size_t bytes) -> void* {
        void* p = w + off;
        off = (off + bytes + 255) & ~(size_t)255;
        return p;
    };

    int*   cnt    = (int*)alloc((size_t)N * 4);
    int*   rowptr = (int*)alloc((size_t)(N + 1) * 4);
    int*   bsum   = (int*)alloc(4096 * 4);
    int*   cursor = (int*)alloc((size_t)N * 4);
    float* dinv   = (float*)alloc((size_t)N * 4);
    float* snorm  = (float*)alloc((size_t)N * 4);
    int2*  eprec  = (int2*)alloc((size_t)E * 8);
    float* hbuf   = (float*)alloc((size_t)N * 32 * 4);
    float* x1     = (float*)alloc((size_t)N * 32 * 4);
    float* x2     = (float*)alloc((size_t)N * 32 * 4);
    float* x3     = (float*)alloc((size_t)N * 32 * 4);
    float* h4     = (float*)alloc((size_t)N * 4);
    float* x4     = (float*)alloc((size_t)N * 4);
    int*   gstart = (int*)alloc((size_t)(NGRAPH + 1) * 4);
    int*   topi   = (int*)alloc((size_t)NGRAPH * TOPK * 4);

    hipMemsetAsync(cnt, 0, (size_t)N * 4, stream);
    hipMemsetAsync(cursor, 0, (size_t)N * 4, stream);

    count_edges<<<(E + TPB - 1) / TPB, TPB, 0, stream>>>(src, dst, cnt, E);
    deg_finish<<<(N + TPB - 1) / TPB, TPB, 0, stream>>>(cnt, dinv, snorm, N);

    int nb = (N + 1023) / 1024;
    scan1<<<nb, 256, 0, stream>>>(cnt, rowptr, bsum, N);
    scan2<<<1, 256, 0, stream>>>(bsum, nb);
    scan3<<<(N + TPB - 1) / TPB, TPB, 0, stream>>>(rowptr, bsum, N, nb);

    const int NSLICES = 128;
    const int nper = (N + 7) / 8;
    scatter_edges_xcd<<<8 * NSLICES, TPB, 0, stream>>>(src, dst, rowptr, cursor, dinv,
                                                       eprec, E, nper, NSLICES);

    // layer 1
    mm_128_32<<<(N + 7) / 8, 256, 0, stream>>>(x, W1, hbuf, N);
    agg32<<<((size_t)N * 8 + TPB - 1) / TPB, TPB, 0, stream>>>(hbuf, eprec, rowptr,
                                                               snorm, b1, x1, N);
    // layer 2
    mm_32_32<<<(N + 7) / 8, 256, 0, stream>>>(x1, W2, hbuf, N);
    agg32<<<((size_t)N * 8 + TPB - 1) / TPB, TPB, 0, stream>>>(hbuf, eprec, rowptr,
                                                               snorm, b2, x2, N);
    // layer 3
    mm_32_32<<<(N + 7) / 8, 256, 0, stream>>>(x2, W3, hbuf, N);
    agg32<<<((size_t)N * 8 + TPB - 1) / TPB, TPB, 0, stream>>>(hbuf, eprec, rowptr,
                                                               snorm, b3, x3, N);
    // layer 4
    mm_32_1<<<((size_t)N * 8 + TPB - 1) / TPB, TPB, 0, stream>>>(x3, W4, h4, N);
    agg1<<<(N + TPB - 1) / TPB, TPB, 0, stream>>>(h4, eprec, rowptr, snorm, b4, x4, N);

    // topk + head
    graph_start<<<(N + TPB - 1) / TPB, TPB, 0, stream>>>(batch, gstart, N, NGRAPH);
    topk_kernel<<<NGRAPH, 64, 0, stream>>>(x4, gstart, topi);
    head_kernel<<<NGRAPH, 256, 0, stream>>>(x1, x2, x3, x4, topi, w5, b5, w6, b6,
                                            fw1, fb1, fw2, fb2, (float*)d_out);
}

// Round 6
// 755.800 us; speedup vs baseline: 1.1846x; 1.1846x over previous
//
#include <hip/hip_runtime.h>
#include <math.h>

#define TPB 256
#define TOPK 30
#define NGRAPH 128
#define TKCAP 4096
#define BSHIFT 11
#define NBMAX 128

// ---------------- CSR build ----------------

__global__ void count_edges(const int* __restrict__ src, const int* __restrict__ dst,
                            int* __restrict__ cnt, int E) {
    int e = blockIdx.x * blockDim.x + threadIdx.x;
    if (e >= E) return;
    int s = src[e], d = dst[e];
    if (s != d) atomicAdd(&cnt[d], 1);
}

__global__ void deg_finish(const int* __restrict__ cnt, float* __restrict__ dinv,
                           float* __restrict__ snorm, int n) {
    int i = blockIdx.x * blockDim.x + threadIdx.x;
    if (i >= n) return;
    float deg = (float)cnt[i] + 1.0f;
    dinv[i] = 1.0f / sqrtf(deg);
    snorm[i] = 1.0f / deg;
}

// exclusive scan, 1024 elems per block
__global__ void scan1(const int* __restrict__ cnt, int* __restrict__ outp,
                      int* __restrict__ bsum, int n) {
    __shared__ int ls[256];
    int t = threadIdx.x;
    int base = blockIdx.x * 1024;
    int v[4], ex[4];
    int run = 0;
    #pragma unroll
    for (int j = 0; j < 4; ++j) {
        int i = base + t * 4 + j;
        v[j] = (i < n) ? cnt[i] : 0;
        ex[j] = run;
        run += v[j];
    }
    ls[t] = run;
    __syncthreads();
    for (int o2 = 1; o2 < 256; o2 <<= 1) {
        int xv = 0;
        if (t >= o2) xv = ls[t - o2];
        __syncthreads();
        ls[t] += xv;
        __syncthreads();
    }
    int tbase = ls[t] - run;   // exclusive base for this thread
    #pragma unroll
    for (int j = 0; j < 4; ++j) {
        int i = base + t * 4 + j;
        if (i < n) outp[i] = tbase + ex[j];
    }
    if (t == 255) bsum[blockIdx.x] = ls[255];
}

__global__ void scan2(int* __restrict__ bsum, int nb) {
    __shared__ int ls[256];
    int t = threadIdx.x;
    int v = (t < nb) ? bsum[t] : 0;
    ls[t] = v;
    __syncthreads();
    for (int o2 = 1; o2 < 256; o2 <<= 1) {
        int xv = 0;
        if (t >= o2) xv = ls[t - o2];
        __syncthreads();
        ls[t] += xv;
        __syncthreads();
    }
    if (t < nb) bsum[t] = ls[t] - v;     // exclusive
    if (t == 255) bsum[nb] = ls[255];    // total
}

__global__ void scan3(int* __restrict__ rowptr, const int* __restrict__ bsum, int n, int nb) {
    int i = blockIdx.x * blockDim.x + threadIdx.x;
    if (i < n) rowptr[i] += bsum[i >> 10];
    if (i == 0) rowptr[n] = bsum[nb];
}

// Phase 1: bin edges by dst-bucket (2048-node ranges) into scratch, laid out in
// CSR-bucket order. Per-(block,bucket) runs are contiguous (~170B) -> write amp ~1.
__global__ void bin_edges(const int* __restrict__ src, const int* __restrict__ dst,
                          const int* __restrict__ rowptr, int* __restrict__ gcur,
                          int2* __restrict__ scratch, int E) {
    __shared__ int2 eds[2048];
    __shared__ int bcnt[NBMAX], bbase[NBMAX], boff[NBMAX];
    int t = threadIdx.x;
    int base = blockIdx.x * 2048;
    int lim = E - base; if (lim > 2048) lim = 2048;
    for (int i = t; i < NBMAX; i += 256) { bcnt[i] = 0; boff[i] = 0; }
    __syncthreads();
    for (int i = t; i < lim; i += 256) {
        int s = src[base + i], d = dst[base + i];
        if (s == d) d = -1;                  // drop self-loops (not in CSR counts)
        eds[i] = make_int2(s, d);
        if (d >= 0) atomicAdd(&bcnt[d >> BSHIFT], 1);
    }
    __syncthreads();
    for (int i = t; i < NBMAX; i += 256) {
        if (bcnt[i] > 0)
            bbase[i] = rowptr[i << BSHIFT] + atomicAdd(&gcur[i], bcnt[i]);
    }
    __syncthreads();
    for (int i = t; i < lim; i += 256) {
        int2 ed = eds[i];
        if (ed.y >= 0) {
            int b = ed.y >> BSHIFT;
            int pos = bbase[b] + atomicAdd(&boff[b], 1);
            scratch[pos] = ed;
        }
    }
}

// Phase 2: one block per bucket. Sequential read of the bucket's scratch span,
// scatter into the bucket's contiguous ~256KB CSR region via LDS cursors.
// All writes to a line happen within this block's short sweep -> L2 merges.
__global__ void scatter_bucket(const int2* __restrict__ scratch,
                               const int* __restrict__ rowptr,
                               const float* __restrict__ dinv,
                               int2* __restrict__ eprec, int N) {
    __shared__ int lcur[1 << BSHIFT];
    int b = blockIdx.x;
    int t = threadIdx.x;
    int nlo = b << BSHIFT;
    int nhi = nlo + (1 << BSHIFT); if (nhi > N) nhi = N;
    int lo = rowptr[nlo], hi = rowptr[nhi];
    for (int i = t; i < (1 << BSHIFT); i += 256) lcur[i] = 0;
    __syncthreads();
    for (int e = lo + t; e < hi; e += 256) {
        int2 ed = scratch[e];
        int d = ed.y;
        int p = rowptr[d] + atomicAdd(&lcur[d - nlo], 1);
        eprec[p] = make_int2(ed.x, __float_as_int(dinv[ed.x] * dinv[d]));
    }
}

// ---------------- GEMMs ----------------

__global__ void mm_128_32(const float* __restrict__ X, const float* __restrict__ W,
                          float* __restrict__ H, int n) {
    __shared__ float Ws[128 * 32];
    __shared__ float xs[8 * 128];
    int t = threadIdx.x;
    for (int i = t; i < 128 * 32; i += 256) Ws[i] = W[i];
    int rbase = blockIdx.x * 8;
    {
        int i = t * 4;  // 0..1020, covers all 1024
        int rr = rbase + (i >> 7);
        float4 v = make_float4(0.f, 0.f, 0.f, 0.f);
        if (rr < n) v = *(const float4*)(X + (long)rbase * 128 + i);
        *(float4*)(xs + i) = v;
    }
    __syncthreads();
    int c = t & 31, r = t >> 5;
    int row = rbase + r;
    if (row >= n) return;
    float acc = 0.f;
    #pragma unroll 16
    for (int k = 0; k < 128; ++k) acc += xs[r * 128 + k] * Ws[k * 32 + c];
    H[(long)row * 32 + c] = acc;
}

__global__ void mm_32_32(const float* __restrict__ X, const float* __restrict__ W,
                         float* __restrict__ H, int n) {
    __shared__ float Ws[32 * 32];
    __shared__ float xs[8 * 32];
    int t = threadIdx.x;
    for (int i = t; i < 32 * 32; i += 256) Ws[i] = W[i];
    int rbase = blockIdx.x * 8;
    {
        int rr = rbase + (t >> 5);
        xs[t] = (rr < n) ? X[(long)rbase * 32 + t] : 0.f;
    }
    __syncthreads();
    int c = t & 31, r = t >> 5;
    int row = rbase + r;
    if (row >= n) return;
    float acc = 0.f;
    #pragma unroll
    for (int k = 0; k < 32; ++k) acc += xs[r * 32 + k] * Ws[k * 32 + c];
    H[(long)row * 32 + c] = acc;
}

__global__ void mm_32_1(const float* __restrict__ X, const float* __restrict__ W,
                        float* __restrict__ H4, int n) {
    int gid = blockIdx.x * blockDim.x + threadIdx.x;
    int node = gid >> 3, l = gid & 7;
    if (node >= n) return;
    float4 v = *(const float4*)(X + (long)node * 32 + l * 4);
    float s = v.x * W[l * 4] + v.y * W[l * 4 + 1] + v.z * W[l * 4 + 2] + v.w * W[l * 4 + 3];
    s += __shfl_xor(s, 1, 64);
    s += __shfl_xor(s, 2, 64);
    s += __shfl_xor(s, 4, 64);
    if (l == 0) H4[node] = s;
}

// ---------------- edge aggregation (gather) ----------------

__global__ void agg32(const float* __restrict__ H, const int2* __restrict__ eprec,
                      const int* __restrict__ rowptr,
                      const float* __restrict__ snorm, const float* __restrict__ bias,
                      float* __restrict__ OUT, int n) {
    int gid = blockIdx.x * blockDim.x + threadIdx.x;
    int node = gid >> 3, l = gid & 7;
    if (node >= n) return;
    int beg = rowptr[node], end = rowptr[node + 1];
    float ax = 0.f, ay = 0.f, az = 0.f, aw = 0.f;
    int e0 = beg;
    // full batches of 8: unrolled, 8 independent gathers in flight
    for (; e0 + 8 <= end; e0 += 8) {
        int2 ed = eprec[e0 + l];       // coalesced: 8 lanes load 8 consecutive edges
        int ss[8]; float ww[8];
        #pragma unroll
        for (int j = 0; j < 8; ++j) {
            ss[j] = __shfl(ed.x, j, 8);
            ww[j] = __shfl(__int_as_float(ed.y), j, 8);
        }
        float4 hv[8];
        #pragma unroll
        for (int j = 0; j < 8; ++j)
            hv[j] = *(const float4*)(H + (long)ss[j] * 32 + l * 4);
        #pragma unroll
        for (int j = 0; j < 8; ++j) {
            ax += hv[j].x * ww[j]; ay += hv[j].y * ww[j];
            az += hv[j].z * ww[j]; aw += hv[j].w * ww[j];
        }
    }
    // tail
    if (e0 < end) {
        int m = end - e0;
        int2 ed = (l < m) ? eprec[e0 + l] : make_int2(0, 0);
        for (int j = 0; j < m; ++j) {
            int s = __shfl(ed.x, j, 8);
            float w = __shfl(__int_as_float(ed.y), j, 8);
            float4 hv = *(const float4*)(H + (long)s * 32 + l * 4);
            ax += hv.x * w; ay += hv.y * w; az += hv.z * w; aw += hv.w * w;
        }
    }
    float sn = snorm[node];
    float4 hv = *(const float4*)(H + (long)node * 32 + l * 4);
    float4 bv = *(const float4*)(bias + l * 4);
    float4 o;
    o.x = tanhf(ax + hv.x * sn + bv.x);
    o.y = tanhf(ay + hv.y * sn + bv.y);
    o.z = tanhf(az + hv.z * sn + bv.z);
    o.w = tanhf(aw + hv.w * sn + bv.w);
    *(float4*)(OUT + (long)node * 32 + l * 4) = o;
}

__global__ void agg1(const float* __restrict__ H4, const int2* __restrict__ eprec,
                     const int* __restrict__ rowptr,
                     const float* __restrict__ snorm, const float* __restrict__ b4,
                     float* __restrict__ X4, int n) {
    int node = blockIdx.x * blockDim.x + threadIdx.x;
    if (node >= n) return;
    int beg = rowptr[node], end = rowptr[node + 1];
    float acc = 0.f;
    for (int e = beg; e < end; ++e) {
        int2 ed = eprec[e];
        acc += H4[ed.x] * __int_as_float(ed.y);
    }
    X4[node] = tanhf(acc + H4[node] * snorm[node] + b4[0]);
}

// ---------------- topk per graph: 1 wave, LDS-staged argmax-with-marking ----------------

__global__ void graph_start(const int* __restrict__ batch, int* __restrict__ gstart,
                            int n, int B) {
    int i = blockIdx.x * blockDim.x + threadIdx.x;
    if (i >= n) return;
    int b = batch[i];
    int bp = (i == 0) ? -1 : batch[i - 1];
    for (int g = bp + 1; g <= b; ++g) gstart[g] = i;
    if (i == n - 1) {
        for (int g = b + 1; g <= B; ++g) gstart[g] = n;
    }
}

__global__ __launch_bounds__(64) void topk_kernel(const float* __restrict__ keyf,
                                                  const int* __restrict__ gstart,
                                                  int* __restrict__ topi) {
    int g = blockIdx.x;
    int t = threadIdx.x;  // 0..63, single wave
    __shared__ float vals[TKCAP];
    __shared__ int selg[TOPK];
    int beg = gstart[g], end = gstart[g + 1];
    int range = end - beg;
    int lim = range < TKCAP ? range : TKCAP;
    for (int i = t; i < lim; i += 64) vals[i] = keyf[beg + i];
    __syncthreads();
    for (int k = 0; k < TOPK; ++k) {
        float best = -INFINITY;
        int bi = 0x7fffffff;
        // LDS region: strict > keeps lowest index within a lane
        for (int i = t; i < lim; i += 64) {
            float v = vals[i];
            if (v > best) { best = v; bi = i; }
        }
        // overflow region from global (never triggered at range<=TKCAP)
        for (int i = TKCAP + t; i < range; i += 64) {
            int gi = beg + i;
            bool taken = false;
            for (int j = 0; j < k; ++j)
                if (selg[j] == gi) { taken = true; break; }
            if (taken) continue;
            float v = keyf[gi];
            if (v > best || (v == best && i < bi)) { best = v; bi = i; }
        }
        // wave argmax reduce, tie -> lower index
        #pragma unroll
        for (int off = 1; off < 64; off <<= 1) {
            float ov = __shfl_xor(best, off, 64);
            int oi = __shfl_xor(bi, off, 64);
            if (ov > best || (ov == best && oi < bi)) { best = ov; bi = oi; }
        }
        if (t == 0) {
            int gl = (bi == 0x7fffffff) ? -1 : beg + bi;
            selg[k] = gl;
            topi[g * TOPK + k] = gl;
            if (bi != 0x7fffffff && bi < TKCAP) vals[bi] = -INFINITY;
        }
        __syncthreads();
    }
}

// ---------------- head: conv5 -> pool -> conv6 -> fc1 -> fc2 -> log_softmax ----------------

__global__ void head_kernel(const float* __restrict__ x1, const float* __restrict__ x2,
                            const float* __restrict__ x3, const float* __restrict__ x4,
                            const int* __restrict__ topi,
                            const float* __restrict__ w5, const float* __restrict__ b5,
                            const float* __restrict__ w6, const float* __restrict__ b6,
                            const float* __restrict__ fw1, const float* __restrict__ fb1,
                            const float* __restrict__ fw2, const float* __restrict__ fb2,
                            float* __restrict__ out) {
    int b = blockIdx.x;
    int t = threadIdx.x;
    __shared__ float feats[TOPK][97];
    __shared__ float c5[16][30];
    __shared__ float p6[16][15];
    __shared__ float z[352];
    __shared__ float hh[128];
    __shared__ float oo[10];

    for (int idx = t; idx < TOPK * 97; idx += 256) {
        int k = idx / 97, j = idx % 97;
        int node = topi[b * TOPK + k];
        float v = 0.f;
        if (node >= 0) {
            if (j < 32) v = x1[(long)node * 32 + j];
            else if (j < 64) v = x2[(long)node * 32 + (j - 32)];
            else if (j < 96) v = x3[(long)node * 32 + (j - 64)];
            else v = x4[node];
        }
        feats[k][j] = v;
    }
    __syncthreads();

    for (int idx = t; idx < 16 * 30; idx += 256) {
        int oc = idx / 30, k = idx % 30;
        float acc = b5[oc];
        for (int j = 0; j < 97; ++j) acc += w5[oc * 97 + j] * feats[k][j];
        c5[oc][k] = fmaxf(acc, 0.f);
    }
    __syncthreads();

    for (int idx = t; idx < 16 * 15; idx += 256) {
        int oc = idx / 15, k = idx % 15;
        p6[oc][k] = fmaxf(c5[oc][2 * k], c5[oc][2 * k + 1]);
    }
    __syncthreads();

    for (int idx = t; idx < 32 * 11; idx += 256) {
        int oc = idx / 11, tt = idx % 11;
        float acc = b6[oc];
        for (int ic = 0; ic < 16; ++ic)
            for (int j = 0; j < 5; ++j)
                acc += w6[(oc * 16 + ic) * 5 + j] * p6[ic][tt + j];
        z[idx] = fmaxf(acc, 0.f);
    }
    __syncthreads();

    if (t < 128) {
        float acc = fb1[t];
        for (int i = 0; i < 352; ++i) acc += z[i] * fw1[i * 128 + t];
        hh[t] = fmaxf(acc, 0.f);
    }
    __syncthreads();

    if (t < 10) {
        float acc = fb2[t];
        for (int j = 0; j < 128; ++j) acc += hh[j] * fw2[j * 10 + t];
        oo[t] = acc;
    }
    __syncthreads();

    if (t < 10) {
        float m = -INFINITY;
        for (int c = 0; c < 10; ++c) m = fmaxf(m, oo[c]);
        float s = 0.f;
        for (int c = 0; c < 10; ++c) s += expf(oo[c] - m);
        out[b * 10 + t] = oo[t] - m - logf(s);
    }
}

// ---------------- launch ----------------

extern "C" void kernel_launch(void* const* d_in, const int* in_sizes, int n_in,
                              void* d_out, int out_size, void* d_ws, size_t ws_size,
                              hipStream_t stream) {
    const float* x     = (const float*)d_in[0];
    const int*   ei    = (const int*)d_in[1];
    const int*   batch = (const int*)d_in[2];
    const float* W1 = (const float*)d_in[3];
    const float* b1 = (const float*)d_in[4];
    const float* W2 = (const float*)d_in[5];
    const float* b2 = (const float*)d_in[6];
    const float* W3 = (const float*)d_in[7];
    const float* b3 = (const float*)d_in[8];
    const float* W4 = (const float*)d_in[9];
    const float* b4 = (const float*)d_in[10];
    const float* w5 = (const float*)d_in[11];
    const float* b5 = (const float*)d_in[12];
    const float* w6 = (const float*)d_in[13];
    const float* b6 = (const float*)d_in[14];
    const float* fw1 = (const float*)d_in[15];
    const float* fb1 = (const float*)d_in[16];
    const float* fw2 = (const float*)d_in[17];
    const float* fb2 = (const float*)d_in[18];

    const int N = in_sizes[0] / 128;
    const int E = in_sizes[1] / 2;
    const int* src = ei;
    const int* dst = ei + E;

    char* w = (char*)d_ws;
    size_t off = 0;
    auto alloc = [&](size_t bytes) -> void* {
        void* p = w + off;
        off = (off + bytes + 255) & ~(size_t)255;
        return p;
    };

    int*   cnt    = (int*)alloc((size_t)N * 4);
    int*   rowptr = (int*)alloc((size_t)(N + 1) * 4);
    int*   bsum   = (int*)alloc(4096 * 4);
    int*   gcur   = (int*)alloc(NBMAX * 4);
    float* dinv   = (float*)alloc((size_t)N * 4);
    float* snorm  = (float*)alloc((size_t)N * 4);
    int2*  eprec  = (int2*)alloc((size_t)E * 8);
    float* hbuf   = (float*)alloc((size_t)N * 32 * 4);   // also aliased as scratch (E*8 == N*32*4)
    float* x1     = (float*)alloc((size_t)N * 32 * 4);
    float* x2     = (float*)alloc((size_t)N * 32 * 4);
    float* x3     = (float*)alloc((size_t)N * 32 * 4);
    float* h4     = (float*)alloc((size_t)N * 4);
    float* x4     = (float*)alloc((size_t)N * 4);
    int*   gstart = (int*)alloc((size_t)(NGRAPH + 1) * 4);
    int*   topi   = (int*)alloc((size_t)NGRAPH * TOPK * 4);

    int2* scratch = (int2*)hbuf;   // disjoint lifetime: used only before mm_128_32

    hipMemsetAsync(cnt, 0, (size_t)N * 4, stream);
    hipMemsetAsync(gcur, 0, NBMAX * 4, stream);

    count_edges<<<(E + TPB - 1) / TPB, TPB, 0, stream>>>(src, dst, cnt, E);
    deg_finish<<<(N + TPB - 1) / TPB, TPB, 0, stream>>>(cnt, dinv, snorm, N);

    int nb = (N + 1023) / 1024;
    scan1<<<nb, 256, 0, stream>>>(cnt, rowptr, bsum, N);
    scan2<<<1, 256, 0, stream>>>(bsum, nb);
    scan3<<<(N + TPB - 1) / TPB, TPB, 0, stream>>>(rowptr, bsum, N, nb);

    const int NB = (N + (1 << BSHIFT) - 1) >> BSHIFT;
    bin_edges<<<(E + 2047) / 2048, TPB, 0, stream>>>(src, dst, rowptr, gcur, scratch, E);
    scatter_bucket<<<NB, TPB, 0, stream>>>(scratch, rowptr, dinv, eprec, N);

    // layer 1
    mm_128_32<<<(N + 7) / 8, 256, 0, stream>>>(x, W1, hbuf, N);
    agg32<<<((size_t)N * 8 + TPB - 1) / TPB, TPB, 0, stream>>>(hbuf, eprec, rowptr,
                                                               snorm, b1, x1, N);
    // layer 2
    mm_32_32<<<(N + 7) / 8, 256, 0, stream>>>(x1, W2, hbuf, N);
    agg32<<<((size_t)N * 8 + TPB - 1) / TPB, TPB, 0, stream>>>(hbuf, eprec, rowptr,
                                                               snorm, b2, x2, N);
    // layer 3
    mm_32_32<<<(N + 7) / 8, 256, 0, stream>>>(x2, W3, hbuf, N);
    agg32<<<((size_t)N * 8 + TPB - 1) / TPB, TPB, 0, stream>>>(hbuf, eprec, rowptr,
                                                               snorm, b3, x3, N);
    // layer 4
    mm_32_1<<<((size_t)N * 8 + TPB - 1) / TPB, TPB, 0, stream>>>(x3, W4, h4, N);
    agg1<<<(N + TPB - 1) / TPB, TPB, 0, stream>>>(h4, eprec, rowptr, snorm, b4, x4, N);

    // topk + head
    graph_start<<<(N + TPB - 1) / TPB, TPB, 0, stream>>>(batch, gstart, N, NGRAPH);
    topk_kernel<<<NGRAPH, 64, 0, stream>>>(x4, gstart, topi);
    head_kernel<<<NGRAPH, 256, 0, stream>>>(x1, x2, x3, x4, topi, w5, b5, w6, b6,
                                            fw1, fb1, fw2, fb2, (float*)d_out);
}

// Round 7
// 695.338 us; speedup vs baseline: 1.2876x; 1.0870x over previous
//
#include <hip/hip_runtime.h>
#include <math.h>

#define TPB 256
#define TOPK 30
#define NGRAPH 128
#define TKCAP 4096
#define BSHIFT 11
#define NBMAX 128

// ---------------- CSR build (bucket-based, no random global atomics) ----------------

// 1) per-bucket edge histogram: LDS counters + ~98 global atomics per block
__global__ void bhist(const int* __restrict__ src, const int* __restrict__ dst,
                      int* __restrict__ btot, int E) {
    __shared__ int bcnt[NBMAX];
    int t = threadIdx.x;
    int base = blockIdx.x * 2048;
    int lim = E - base; if (lim > 2048) lim = 2048;
    for (int i = t; i < NBMAX; i += 256) bcnt[i] = 0;
    __syncthreads();
    for (int i = t; i < lim; i += 256) {
        int s = src[base + i], d = dst[base + i];
        if (s != d) atomicAdd(&bcnt[d >> BSHIFT], 1);
    }
    __syncthreads();
    for (int i = t; i < NBMAX; i += 256)
        if (bcnt[i] > 0) atomicAdd(&btot[i], bcnt[i]);
}

// 2) exclusive scan of bucket totals (single block, 128 threads)
__global__ void bucket_scan(const int* __restrict__ btot, int* __restrict__ bbase,
                            int nbuckets) {
    __shared__ int ls[NBMAX];
    int t = threadIdx.x;
    int v = (t < nbuckets) ? btot[t] : 0;
    ls[t] = v;
    __syncthreads();
    for (int o = 1; o < NBMAX; o <<= 1) {
        int x = 0;
        if (t >= o) x = ls[t - o];
        __syncthreads();
        ls[t] += x;
        __syncthreads();
    }
    if (t < nbuckets) bbase[t] = ls[t] - v;
}

// 3) bin edges into bucket-major scratch (contiguous per-(block,bucket) runs)
__global__ void bin_edges(const int* __restrict__ src, const int* __restrict__ dst,
                          const int* __restrict__ bbase_g, int* __restrict__ gcur,
                          int2* __restrict__ scratch, int E) {
    __shared__ int2 eds[2048];
    __shared__ int bcnt[NBMAX], bbase[NBMAX], boff[NBMAX];
    int t = threadIdx.x;
    int base = blockIdx.x * 2048;
    int lim = E - base; if (lim > 2048) lim = 2048;
    for (int i = t; i < NBMAX; i += 256) { bcnt[i] = 0; boff[i] = 0; }
    __syncthreads();
    for (int i = t; i < lim; i += 256) {
        int s = src[base + i], d = dst[base + i];
        if (s == d) d = -1;                  // drop self-loops
        eds[i] = make_int2(s, d);
        if (d >= 0) atomicAdd(&bcnt[d >> BSHIFT], 1);
    }
    __syncthreads();
    for (int i = t; i < NBMAX; i += 256) {
        if (bcnt[i] > 0)
            bbase[i] = bbase_g[i] + atomicAdd(&gcur[i], bcnt[i]);
    }
    __syncthreads();
    for (int i = t; i < lim; i += 256) {
        int2 ed = eds[i];
        if (ed.y >= 0) {
            int b = ed.y >> BSHIFT;
            int pos = bbase[b] + atomicAdd(&boff[b], 1);
            scratch[pos] = ed;
        }
    }
}

// 4) per-node counts via LDS histogram over the bucket's scratch span;
//    also emits dinv/snorm (absorbs deg_finish). Coalesced writes only.
__global__ void bucket_count(const int2* __restrict__ scratch,
                             const int* __restrict__ bbase, const int* __restrict__ btot,
                             int* __restrict__ cnt, float* __restrict__ dinv,
                             float* __restrict__ snorm, int N) {
    __shared__ int hist[1 << BSHIFT];
    int b = blockIdx.x, t = threadIdx.x;
    int nlo = b << BSHIFT;
    int nn = N - nlo; if (nn > (1 << BSHIFT)) nn = 1 << BSHIFT;
    for (int i = t; i < (1 << BSHIFT); i += 256) hist[i] = 0;
    __syncthreads();
    int lo = bbase[b], hi = lo + btot[b];
    for (int e = lo + t; e < hi; e += 256)
        atomicAdd(&hist[scratch[e].y - nlo], 1);
    __syncthreads();
    for (int i = t; i < nn; i += 256) {
        int c = hist[i];
        cnt[nlo + i] = c;
        float deg = (float)c + 1.0f;
        dinv[nlo + i] = 1.0f / sqrtf(deg);
        snorm[nlo + i] = 1.0f / deg;
    }
}

// exclusive scan, 1024 elems per block
__global__ void scan1(const int* __restrict__ cnt, int* __restrict__ outp,
                      int* __restrict__ bsum, int n) {
    __shared__ int ls[256];
    int t = threadIdx.x;
    int base = blockIdx.x * 1024;
    int v[4], ex[4];
    int run = 0;
    #pragma unroll
    for (int j = 0; j < 4; ++j) {
        int i = base + t * 4 + j;
        v[j] = (i < n) ? cnt[i] : 0;
        ex[j] = run;
        run += v[j];
    }
    ls[t] = run;
    __syncthreads();
    for (int o2 = 1; o2 < 256; o2 <<= 1) {
        int xv = 0;
        if (t >= o2) xv = ls[t - o2];
        __syncthreads();
        ls[t] += xv;
        __syncthreads();
    }
    int tbase = ls[t] - run;   // exclusive base for this thread
    #pragma unroll
    for (int j = 0; j < 4; ++j) {
        int i = base + t * 4 + j;
        if (i < n) outp[i] = tbase + ex[j];
    }
    if (t == 255) bsum[blockIdx.x] = ls[255];
}

__global__ void scan2(int* __restrict__ bsum, int nb) {
    __shared__ int ls[256];
    int t = threadIdx.x;
    int v = (t < nb) ? bsum[t] : 0;
    ls[t] = v;
    __syncthreads();
    for (int o2 = 1; o2 < 256; o2 <<= 1) {
        int xv = 0;
        if (t >= o2) xv = ls[t - o2];
        __syncthreads();
        ls[t] += xv;
        __syncthreads();
    }
    if (t < nb) bsum[t] = ls[t] - v;     // exclusive
    if (t == 255) bsum[nb] = ls[255];    // total
}

__global__ void scan3(int* __restrict__ rowptr, const int* __restrict__ bsum, int n, int nb) {
    int i = blockIdx.x * blockDim.x + threadIdx.x;
    if (i < n) rowptr[i] += bsum[i >> 10];
    if (i == 0) rowptr[n] = bsum[nb];
}

// 5) one block per bucket: sweep bucket's scratch span, scatter into the
//    bucket's contiguous CSR region via LDS cursors (L2-merged writes).
__global__ void scatter_bucket(const int2* __restrict__ scratch,
                               const int* __restrict__ bbase, const int* __restrict__ btot,
                               const int* __restrict__ rowptr,
                               const float* __restrict__ dinv,
                               int2* __restrict__ eprec, int N) {
    __shared__ int lcur[1 << BSHIFT];
    int b = blockIdx.x;
    int t = threadIdx.x;
    int nlo = b << BSHIFT;
    int lo = bbase[b], hi = lo + btot[b];
    for (int i = t; i < (1 << BSHIFT); i += 256) lcur[i] = 0;
    __syncthreads();
    for (int e = lo + t; e < hi; e += 256) {
        int2 ed = scratch[e];
        int d = ed.y;
        int p = rowptr[d] + atomicAdd(&lcur[d - nlo], 1);
        eprec[p] = make_int2(ed.x, __float_as_int(dinv[ed.x] * dinv[d]));
    }
}

// ---------------- GEMMs ----------------

__global__ void mm_128_32(const float* __restrict__ X, const float* __restrict__ W,
                          float* __restrict__ H, int n) {
    __shared__ float Ws[128 * 32];
    __shared__ float xs[8 * 128];
    int t = threadIdx.x;
    for (int i = t; i < 128 * 32; i += 256) Ws[i] = W[i];
    int rbase = blockIdx.x * 8;
    {
        int i = t * 4;  // 0..1020, covers all 1024
        int rr = rbase + (i >> 7);
        float4 v = make_float4(0.f, 0.f, 0.f, 0.f);
        if (rr < n) v = *(const float4*)(X + (long)rbase * 128 + i);
        *(float4*)(xs + i) = v;
    }
    __syncthreads();
    int c = t & 31, r = t >> 5;
    int row = rbase + r;
    if (row >= n) return;
    float acc = 0.f;
    #pragma unroll 16
    for (int k = 0; k < 128; ++k) acc += xs[r * 128 + k] * Ws[k * 32 + c];
    H[(long)row * 32 + c] = acc;
}

__global__ void mm_32_32(const float* __restrict__ X, const float* __restrict__ W,
                         float* __restrict__ H, int n) {
    __shared__ float Ws[32 * 32];
    __shared__ float xs[8 * 32];
    int t = threadIdx.x;
    for (int i = t; i < 32 * 32; i += 256) Ws[i] = W[i];
    int rbase = blockIdx.x * 8;
    {
        int rr = rbase + (t >> 5);
        xs[t] = (rr < n) ? X[(long)rbase * 32 + t] : 0.f;
    }
    __syncthreads();
    int c = t & 31, r = t >> 5;
    int row = rbase + r;
    if (row >= n) return;
    float acc = 0.f;
    #pragma unroll
    for (int k = 0; k < 32; ++k) acc += xs[r * 32 + k] * Ws[k * 32 + c];
    H[(long)row * 32 + c] = acc;
}

__global__ void mm_32_1(const float* __restrict__ X, const float* __restrict__ W,
                        float* __restrict__ H4, int n) {
    int gid = blockIdx.x * blockDim.x + threadIdx.x;
    int node = gid >> 3, l = gid & 7;
    if (node >= n) return;
    float4 v = *(const float4*)(X + (long)node * 32 + l * 4);
    float s = v.x * W[l * 4] + v.y * W[l * 4 + 1] + v.z * W[l * 4 + 2] + v.w * W[l * 4 + 3];
    s += __shfl_xor(s, 1, 64);
    s += __shfl_xor(s, 2, 64);
    s += __shfl_xor(s, 4, 64);
    if (l == 0) H4[node] = s;
}

// ---------------- edge aggregation (gather) ----------------

__global__ void agg32(const float* __restrict__ H, const int2* __restrict__ eprec,
                      const int* __restrict__ rowptr,
                      const float* __restrict__ snorm, const float* __restrict__ bias,
                      float* __restrict__ OUT, int n) {
    int gid = blockIdx.x * blockDim.x + threadIdx.x;
    int node = gid >> 3, l = gid & 7;
    if (node >= n) return;
    int beg = rowptr[node], end = rowptr[node + 1];
    float ax = 0.f, ay = 0.f, az = 0.f, aw = 0.f;
    int e0 = beg;
    // full batches of 8: unrolled, 8 independent gathers in flight
    for (; e0 + 8 <= end; e0 += 8) {
        int2 ed = eprec[e0 + l];       // coalesced: 8 lanes load 8 consecutive edges
        int ss[8]; float ww[8];
        #pragma unroll
        for (int j = 0; j < 8; ++j) {
            ss[j] = __shfl(ed.x, j, 8);
            ww[j] = __shfl(__int_as_float(ed.y), j, 8);
        }
        float4 hv[8];
        #pragma unroll
        for (int j = 0; j < 8; ++j)
            hv[j] = *(const float4*)(H + (long)ss[j] * 32 + l * 4);
        #pragma unroll
        for (int j = 0; j < 8; ++j) {
            ax += hv[j].x * ww[j]; ay += hv[j].y * ww[j];
            az += hv[j].z * ww[j]; aw += hv[j].w * ww[j];
        }
    }
    // tail
    if (e0 < end) {
        int m = end - e0;
        int2 ed = (l < m) ? eprec[e0 + l] : make_int2(0, 0);
        for (int j = 0; j < m; ++j) {
            int s = __shfl(ed.x, j, 8);
            float w = __shfl(__int_as_float(ed.y), j, 8);
            float4 hv = *(const float4*)(H + (long)s * 32 + l * 4);
            ax += hv.x * w; ay += hv.y * w; az += hv.z * w; aw += hv.w * w;
        }
    }
    float sn = snorm[node];
    float4 hv = *(const float4*)(H + (long)node * 32 + l * 4);
    float4 bv = *(const float4*)(bias + l * 4);
    float4 o;
    o.x = tanhf(ax + hv.x * sn + bv.x);
    o.y = tanhf(ay + hv.y * sn + bv.y);
    o.z = tanhf(az + hv.z * sn + bv.z);
    o.w = tanhf(aw + hv.w * sn + bv.w);
    *(float4*)(OUT + (long)node * 32 + l * 4) = o;
}

__global__ void agg1(const float* __restrict__ H4, const int2* __restrict__ eprec,
                     const int* __restrict__ rowptr,
                     const float* __restrict__ snorm, const float* __restrict__ b4,
                     float* __restrict__ X4, int n) {
    int node = blockIdx.x * blockDim.x + threadIdx.x;
    if (node >= n) return;
    int beg = rowptr[node], end = rowptr[node + 1];
    float acc = 0.f;
    for (int e = beg; e < end; ++e) {
        int2 ed = eprec[e];
        acc += H4[ed.x] * __int_as_float(ed.y);
    }
    X4[node] = tanhf(acc + H4[node] * snorm[node] + b4[0]);
}

// ---------------- topk per graph: 1 wave, LDS-staged argmax-with-marking ----------------

__global__ void graph_start(const int* __restrict__ batch, int* __restrict__ gstart,
                            int n, int B) {
    int i = blockIdx.x * blockDim.x + threadIdx.x;
    if (i >= n) return;
    int b = batch[i];
    int bp = (i == 0) ? -1 : batch[i - 1];
    for (int g = bp + 1; g <= b; ++g) gstart[g] = i;
    if (i == n - 1) {
        for (int g = b + 1; g <= B; ++g) gstart[g] = n;
    }
}

__global__ __launch_bounds__(64) void topk_kernel(const float* __restrict__ keyf,
                                                  const int* __restrict__ gstart,
                                                  int* __restrict__ topi) {
    int g = blockIdx.x;
    int t = threadIdx.x;  // 0..63, single wave
    __shared__ float vals[TKCAP];
    __shared__ int selg[TOPK];
    int beg = gstart[g], end = gstart[g + 1];
    int range = end - beg;
    int lim = range < TKCAP ? range : TKCAP;
    for (int i = t; i < lim; i += 64) vals[i] = keyf[beg + i];
    __syncthreads();
    for (int k = 0; k < TOPK; ++k) {
        float best = -INFINITY;
        int bi = 0x7fffffff;
        // LDS region: strict > keeps lowest index within a lane
        for (int i = t; i < lim; i += 64) {
            float v = vals[i];
            if (v > best) { best = v; bi = i; }
        }
        // overflow region from global (never triggered at range<=TKCAP)
        for (int i = TKCAP + t; i < range; i += 64) {
            int gi = beg + i;
            bool taken = false;
            for (int j = 0; j < k; ++j)
                if (selg[j] == gi) { taken = true; break; }
            if (taken) continue;
            float v = keyf[gi];
            if (v > best || (v == best && i < bi)) { best = v; bi = i; }
        }
        // wave argmax reduce, tie -> lower index
        #pragma unroll
        for (int off = 1; off < 64; off <<= 1) {
            float ov = __shfl_xor(best, off, 64);
            int oi = __shfl_xor(bi, off, 64);
            if (ov > best || (ov == best && oi < bi)) { best = ov; bi = oi; }
        }
        if (t == 0) {
            int gl = (bi == 0x7fffffff) ? -1 : beg + bi;
            selg[k] = gl;
            topi[g * TOPK + k] = gl;
            if (bi != 0x7fffffff && bi < TKCAP) vals[bi] = -INFINITY;
        }
        __syncthreads();
    }
}

// ---------------- head: conv5 -> pool -> conv6 -> fc1 -> fc2 -> log_softmax ----------------

__global__ void head_kernel(const float* __restrict__ x1, const float* __restrict__ x2,
                            const float* __restrict__ x3, const float* __restrict__ x4,
                            const int* __restrict__ topi,
                            const float* __restrict__ w5, const float* __restrict__ b5,
                            const float* __restrict__ w6, const float* __restrict__ b6,
                            const float* __restrict__ fw1, const float* __restrict__ fb1,
                            const float* __restrict__ fw2, const float* __restrict__ fb2,
                            float* __restrict__ out) {
    int b = blockIdx.x;
    int t = threadIdx.x;
    __shared__ float feats[TOPK][97];
    __shared__ float c5[16][30];
    __shared__ float p6[16][15];
    __shared__ float z[352];
    __shared__ float hh[128];
    __shared__ float oo[10];

    for (int idx = t; idx < TOPK * 97; idx += 256) {
        int k = idx / 97, j = idx % 97;
        int node = topi[b * TOPK + k];
        float v = 0.f;
        if (node >= 0) {
            if (j < 32) v = x1[(long)node * 32 + j];
            else if (j < 64) v = x2[(long)node * 32 + (j - 32)];
            else if (j < 96) v = x3[(long)node * 32 + (j - 64)];
            else v = x4[node];
        }
        feats[k][j] = v;
    }
    __syncthreads();

    for (int idx = t; idx < 16 * 30; idx += 256) {
        int oc = idx / 30, k = idx % 30;
        float acc = b5[oc];
        for (int j = 0; j < 97; ++j) acc += w5[oc * 97 + j] * feats[k][j];
        c5[oc][k] = fmaxf(acc, 0.f);
    }
    __syncthreads();

    for (int idx = t; idx < 16 * 15; idx += 256) {
        int oc = idx / 15, k = idx % 15;
        p6[oc][k] = fmaxf(c5[oc][2 * k], c5[oc][2 * k + 1]);
    }
    __syncthreads();

    for (int idx = t; idx < 32 * 11; idx += 256) {
        int oc = idx / 11, tt = idx % 11;
        float acc = b6[oc];
        for (int ic = 0; ic < 16; ++ic)
            for (int j = 0; j < 5; ++j)
                acc += w6[(oc * 16 + ic) * 5 + j] * p6[ic][tt + j];
        z[idx] = fmaxf(acc, 0.f);
    }
    __syncthreads();

    if (t < 128) {
        float acc = fb1[t];
        for (int i = 0; i < 352; ++i) acc += z[i] * fw1[i * 128 + t];
        hh[t] = fmaxf(acc, 0.f);
    }
    __syncthreads();

    if (t < 10) {
        float acc = fb2[t];
        for (int j = 0; j < 128; ++j) acc += hh[j] * fw2[j * 10 + t];
        oo[t] = acc;
    }
    __syncthreads();

    if (t < 10) {
        float m = -INFINITY;
        for (int c = 0; c < 10; ++c) m = fmaxf(m, oo[c]);
        float s = 0.f;
        for (int c = 0; c < 10; ++c) s += expf(oo[c] - m);
        out[b * 10 + t] = oo[t] - m - logf(s);
    }
}

// ---------------- launch ----------------

extern "C" void kernel_launch(void* const* d_in, const int* in_sizes, int n_in,
                              void* d_out, int out_size, void* d_ws, size_t ws_size,
                              hipStream_t stream) {
    const float* x     = (const float*)d_in[0];
    const int*   ei    = (const int*)d_in[1];
    const int*   batch = (const int*)d_in[2];
    const float* W1 = (const float*)d_in[3];
    const float* b1 = (const float*)d_in[4];
    const float* W2 = (const float*)d_in[5];
    const float* b2 = (const float*)d_in[6];
    const float* W3 = (const float*)d_in[7];
    const float* b3 = (const float*)d_in[8];
    const float* W4 = (const float*)d_in[9];
    const float* b4 = (const float*)d_in[10];
    const float* w5 = (const float*)d_in[11];
    const float* b5 = (const float*)d_in[12];
    const float* w6 = (const float*)d_in[13];
    const float* b6 = (const float*)d_in[14];
    const float* fw1 = (const float*)d_in[15];
    const float* fb1 = (const float*)d_in[16];
    const float* fw2 = (const float*)d_in[17];
    const float* fb2 = (const float*)d_in[18];

    const int N = in_sizes[0] / 128;
    const int E = in_sizes[1] / 2;
    const int* src = ei;
    const int* dst = ei + E;

    char* w = (char*)d_ws;
    size_t off = 0;
    auto alloc = [&](size_t bytes) -> void* {
        void* p = w + off;
        off = (off + bytes + 255) & ~(size_t)255;
        return p;
    };

    int*   cnt    = (int*)alloc((size_t)N * 4);
    int*   rowptr = (int*)alloc((size_t)(N + 1) * 4);
    int*   bsum   = (int*)alloc(4096 * 4);
    int*   gcur   = (int*)alloc(NBMAX * 4);
    int*   btot   = (int*)alloc(NBMAX * 4);
    int*   bbase  = (int*)alloc(NBMAX * 4);
    float* dinv   = (float*)alloc((size_t)N * 4);
    float* snorm  = (float*)alloc((size_t)N * 4);
    int2*  eprec  = (int2*)alloc((size_t)E * 8);
    float* hbuf   = (float*)alloc((size_t)N * 32 * 4);   // aliased as scratch (E*8 == N*32*4)
    float* x1     = (float*)alloc((size_t)N * 32 * 4);
    float* x2     = (float*)alloc((size_t)N * 32 * 4);
    float* x3     = (float*)alloc((size_t)N * 32 * 4);
    float* h4     = (float*)alloc((size_t)N * 4);
    float* x4     = (float*)alloc((size_t)N * 4);
    int*   gstart = (int*)alloc((size_t)(NGRAPH + 1) * 4);
    int*   topi   = (int*)alloc((size_t)NGRAPH * TOPK * 4);

    int2* scratch = (int2*)hbuf;   // disjoint lifetime: used only before mm_128_32

    hipMemsetAsync(gcur, 0, NBMAX * 4, stream);
    hipMemsetAsync(btot, 0, NBMAX * 4, stream);

    const int NB = (N + (1 << BSHIFT) - 1) >> BSHIFT;
    const int EB = (E + 2047) / 2048;

    bhist<<<EB, TPB, 0, stream>>>(src, dst, btot, E);
    bucket_scan<<<1, NBMAX, 0, stream>>>(btot, bbase, NB);
    bin_edges<<<EB, TPB, 0, stream>>>(src, dst, bbase, gcur, scratch, E);
    bucket_count<<<NB, TPB, 0, stream>>>(scratch, bbase, btot, cnt, dinv, snorm, N);

    int nb = (N + 1023) / 1024;
    scan1<<<nb, 256, 0, stream>>>(cnt, rowptr, bsum, N);
    scan2<<<1, 256, 0, stream>>>(bsum, nb);
    scan3<<<(N + TPB - 1) / TPB, TPB, 0, stream>>>(rowptr, bsum, N, nb);

    scatter_bucket<<<NB, TPB, 0, stream>>>(scratch, bbase, btot, rowptr, dinv, eprec, N);

    // layer 1
    mm_128_32<<<(N + 7) / 8, 256, 0, stream>>>(x, W1, hbuf, N);
    agg32<<<((size_t)N * 8 + TPB - 1) / TPB, TPB, 0, stream>>>(hbuf, eprec, rowptr,
                                                               snorm, b1, x1, N);
    // layer 2
    mm_32_32<<<(N + 7) / 8, 256, 0, stream>>>(x1, W2, hbuf, N);
    agg32<<<((size_t)N * 8 + TPB - 1) / TPB, TPB, 0, stream>>>(hbuf, eprec, rowptr,
                                                               snorm, b2, x2, N);
    // layer 3
    mm_32_32<<<(N + 7) / 8, 256, 0, stream>>>(x2, W3, hbuf, N);
    agg32<<<((size_t)N * 8 + TPB - 1) / TPB, TPB, 0, stream>>>(hbuf, eprec, rowptr,
                                                               snorm, b3, x3, N);
    // layer 4
    mm_32_1<<<((size_t)N * 8 + TPB - 1) / TPB, TPB, 0, stream>>>(x3, W4, h4, N);
    agg1<<<(N + TPB - 1) / TPB, TPB, 0, stream>>>(h4, eprec, rowptr, snorm, b4, x4, N);

    // topk + head
    graph_start<<<(N + TPB - 1) / TPB, TPB, 0, stream>>>(batch, gstart, N, NGRAPH);
    topk_kernel<<<NGRAPH, 64, 0, stream>>>(x4, gstart, topi);
    head_kernel<<<NGRAPH, 256, 0, stream>>>(x1, x2, x3, x4, topi, w5, b5, w6, b6,
                                            fw1, fb1, fw2, fb2, (float*)d_out);
}

// Round 8
// 659.262 us; speedup vs baseline: 1.3580x; 1.0547x over previous
//
#include <hip/hip_runtime.h>
#include <math.h>

#define TPB 256
#define TOPK 30
#define NGRAPH 128
#define TKCAP 4096
#define BSHIFT 11
#define NBMAX 128
#define FSHIFT 8
#define NFMAX 800
#define FCAP 4608

// ---------------- CSR build (bucket-based, no random global atomics) ----------------

// 1) per-bucket edge histogram: LDS counters + ~98 global atomics per block
__global__ void bhist(const int* __restrict__ src, const int* __restrict__ dst,
                      int* __restrict__ btot, int E) {
    __shared__ int bcnt[NBMAX];
    int t = threadIdx.x;
    int base = blockIdx.x * 2048;
    int lim = E - base; if (lim > 2048) lim = 2048;
    for (int i = t; i < NBMAX; i += 256) bcnt[i] = 0;
    __syncthreads();
    for (int i = t; i < lim; i += 256) {
        int s = src[base + i], d = dst[base + i];
        if (s != d) atomicAdd(&bcnt[d >> BSHIFT], 1);
    }
    __syncthreads();
    for (int i = t; i < NBMAX; i += 256)
        if (bcnt[i] > 0) atomicAdd(&btot[i], bcnt[i]);
}

// 2) exclusive scan of bucket totals (single block)
__global__ void bucket_scan(const int* __restrict__ btot, int* __restrict__ bbase,
                            int nbuckets) {
    __shared__ int ls[NBMAX];
    int t = threadIdx.x;
    int v = (t < nbuckets) ? btot[t] : 0;
    ls[t] = v;
    __syncthreads();
    for (int o = 1; o < NBMAX; o <<= 1) {
        int x = 0;
        if (t >= o) x = ls[t - o];
        __syncthreads();
        ls[t] += x;
        __syncthreads();
    }
    if (t < nbuckets) bbase[t] = ls[t] - v;
}

// 3) bin edges into coarse-bucket-major scratch (contiguous per-(block,bucket) runs)
__global__ void bin_edges(const int* __restrict__ src, const int* __restrict__ dst,
                          const int* __restrict__ bbase_g, int* __restrict__ gcur,
                          int2* __restrict__ scratch, int E) {
    __shared__ int2 eds[2048];
    __shared__ int bcnt[NBMAX], bbase[NBMAX], boff[NBMAX];
    int t = threadIdx.x;
    int base = blockIdx.x * 2048;
    int lim = E - base; if (lim > 2048) lim = 2048;
    for (int i = t; i < NBMAX; i += 256) { bcnt[i] = 0; boff[i] = 0; }
    __syncthreads();
    for (int i = t; i < lim; i += 256) {
        int s = src[base + i], d = dst[base + i];
        if (s == d) d = -1;                  // drop self-loops
        eds[i] = make_int2(s, d);
        if (d >= 0) atomicAdd(&bcnt[d >> BSHIFT], 1);
    }
    __syncthreads();
    for (int i = t; i < NBMAX; i += 256) {
        if (bcnt[i] > 0)
            bbase[i] = bbase_g[i] + atomicAdd(&gcur[i], bcnt[i]);
    }
    __syncthreads();
    for (int i = t; i < lim; i += 256) {
        int2 ed = eds[i];
        if (ed.y >= 0) {
            int b = ed.y >> BSHIFT;
            int pos = bbase[b] + atomicAdd(&boff[b], 1);
            scratch[pos] = ed;
        }
    }
}

// 4) per-node counts via LDS histogram; emits cnt/dinv/snorm.
__global__ void bucket_count(const int2* __restrict__ scratch,
                             const int* __restrict__ bbase, const int* __restrict__ btot,
                             int* __restrict__ cnt, float* __restrict__ dinv,
                             float* __restrict__ snorm, int N) {
    __shared__ int hist[1 << BSHIFT];
    int b = blockIdx.x, t = threadIdx.x;
    int nlo = b << BSHIFT;
    int nn = N - nlo; if (nn > (1 << BSHIFT)) nn = 1 << BSHIFT;
    for (int i = t; i < (1 << BSHIFT); i += 256) hist[i] = 0;
    __syncthreads();
    int lo = bbase[b], hi = lo + btot[b];
    for (int e = lo + t; e < hi; e += 256)
        atomicAdd(&hist[scratch[e].y - nlo], 1);
    __syncthreads();
    for (int i = t; i < nn; i += 256) {
        int c = hist[i];
        cnt[nlo + i] = c;
        float deg = (float)c + 1.0f;
        dinv[nlo + i] = 1.0f / sqrtf(deg);
        snorm[nlo + i] = 1.0f / deg;
    }
}

// exclusive scan, 1024 elems per block
__global__ void scan1(const int* __restrict__ cnt, int* __restrict__ outp,
                      int* __restrict__ bsum, int n) {
    __shared__ int ls[256];
    int t = threadIdx.x;
    int base = blockIdx.x * 1024;
    int v[4], ex[4];
    int run = 0;
    #pragma unroll
    for (int j = 0; j < 4; ++j) {
        int i = base + t * 4 + j;
        v[j] = (i < n) ? cnt[i] : 0;
        ex[j] = run;
        run += v[j];
    }
    ls[t] = run;
    __syncthreads();
    for (int o2 = 1; o2 < 256; o2 <<= 1) {
        int xv = 0;
        if (t >= o2) xv = ls[t - o2];
        __syncthreads();
        ls[t] += xv;
        __syncthreads();
    }
    int tbase = ls[t] - run;   // exclusive base for this thread
    #pragma unroll
    for (int j = 0; j < 4; ++j) {
        int i = base + t * 4 + j;
        if (i < n) outp[i] = tbase + ex[j];
    }
    if (t == 255) bsum[blockIdx.x] = ls[255];
}

__global__ void scan2(int* __restrict__ bsum, int nb) {
    __shared__ int ls[256];
    int t = threadIdx.x;
    int v = (t < nb) ? bsum[t] : 0;
    ls[t] = v;
    __syncthreads();
    for (int o2 = 1; o2 < 256; o2 <<= 1) {
        int xv = 0;
        if (t >= o2) xv = ls[t - o2];
        __syncthreads();
        ls[t] += xv;
        __syncthreads();
    }
    if (t < nb) bsum[t] = ls[t] - v;     // exclusive
    if (t == 255) bsum[nb] = ls[255];    // total
}

__global__ void scan3(int* __restrict__ rowptr, const int* __restrict__ bsum, int n, int nb) {
    int i = blockIdx.x * blockDim.x + threadIdx.x;
    if (i < n) rowptr[i] += bsum[i >> 10];
    if (i == 0) rowptr[n] = bsum[nb];
}

// 5) re-bin coarse-major scratch -> fine-major (256-node) scratch2.
//    Linear chunks of coarse-major data hit only ~2-3 fine buckets -> runs ~4K edges.
__global__ void bin2(const int2* __restrict__ scratch, const int* __restrict__ rowptr,
                     int* __restrict__ fcur, int2* __restrict__ scratch2, int N, int E) {
    __shared__ int fcnt[NFMAX], fbase[NFMAX], foff[NFMAX];
    int t = threadIdx.x;
    int En = rowptr[N];
    int base = blockIdx.x * 8192;
    if (base >= En) return;
    int lim = En - base; if (lim > 8192) lim = 8192;
    for (int i = t; i < NFMAX; i += 256) { fcnt[i] = 0; foff[i] = 0; }
    __syncthreads();
    for (int i = t; i < lim; i += 256) {
        int d = scratch[base + i].y;
        atomicAdd(&fcnt[d >> FSHIFT], 1);
    }
    __syncthreads();
    for (int fi = t; fi < NFMAX; fi += 256) {
        if (fcnt[fi] > 0)
            fbase[fi] = rowptr[fi << FSHIFT] + atomicAdd(&fcur[fi], fcnt[fi]);
    }
    __syncthreads();
    for (int i = t; i < lim; i += 256) {
        int2 ed = scratch[base + i];
        int fi = ed.y >> FSHIFT;
        int pos = fbase[fi] + atomicAdd(&foff[fi], 1);
        scratch2[pos] = ed;
    }
}

// 6) per fine bucket: LDS counting sort -> fully coalesced eprec writes.
__global__ __launch_bounds__(256) void scatter_sort(const int2* __restrict__ scratch2,
                                                    const int* __restrict__ rowptr,
                                                    const float* __restrict__ dinv,
                                                    int2* __restrict__ eprec, int N) {
    __shared__ int srcA[FCAP], dstA[FCAP], inv[FCAP];
    __shared__ int hist[1 << FSHIFT];
    __shared__ int hcur[1 << FSHIFT];
    int f = blockIdx.x, t = threadIdx.x;
    int nlo = f << FSHIFT;
    int nhi = nlo + (1 << FSHIFT); if (nhi > N) nhi = N;
    int lo = rowptr[nlo], hi = rowptr[nhi];
    int span = hi - lo;
    for (int i = t; i < (1 << FSHIFT); i += 256) hist[i] = 0;
    __syncthreads();
    if (span <= FCAP) {
        for (int i = t; i < span; i += 256) {
            int2 ed = scratch2[lo + i];
            srcA[i] = ed.x; dstA[i] = ed.y;
            atomicAdd(&hist[ed.y - nlo], 1);
        }
        __syncthreads();
        // exclusive scan of hist (256 entries, 256 threads)
        int v = hist[t];
        hcur[t] = v;
        __syncthreads();
        for (int o = 1; o < 256; o <<= 1) {
            int x = (t >= o) ? hcur[t - o] : 0;
            __syncthreads();
            hcur[t] += x;
            __syncthreads();
        }
        int excl = hcur[t] - v;
        __syncthreads();
        hcur[t] = excl;
        __syncthreads();
        for (int i = t; i < span; i += 256) {
            int slot = atomicAdd(&hcur[dstA[i] - nlo], 1);
            inv[slot] = i;
        }
        __syncthreads();
        for (int p = t; p < span; p += 256) {
            int i = inv[p];
            int s = srcA[i], d = dstA[i];
            eprec[lo + p] = make_int2(s, __float_as_int(dinv[s] * dinv[d]));
        }
    } else {
        // fallback (span > FCAP, ~never): direct scatter via LDS cursors
        for (int e = lo + t; e < hi; e += 256) {
            int2 ed = scratch2[e];
            int d = ed.y;
            int p = rowptr[d] + atomicAdd(&hist[d - nlo], 1);
            eprec[p] = make_int2(ed.x, __float_as_int(dinv[ed.x] * dinv[d]));
        }
    }
}

// ---------------- GEMMs ----------------

__global__ void mm_128_32(const float* __restrict__ X, const float* __restrict__ W,
                          float* __restrict__ H, int n) {
    __shared__ float Ws[128 * 32];
    __shared__ float xs[8 * 128];
    int t = threadIdx.x;
    for (int i = t; i < 128 * 32; i += 256) Ws[i] = W[i];
    int rbase = blockIdx.x * 8;
    {
        int i = t * 4;  // 0..1020, covers all 1024
        int rr = rbase + (i >> 7);
        float4 v = make_float4(0.f, 0.f, 0.f, 0.f);
        if (rr < n) v = *(const float4*)(X + (long)rbase * 128 + i);
        *(float4*)(xs + i) = v;
    }
    __syncthreads();
    int c = t & 31, r = t >> 5;
    int row = rbase + r;
    if (row >= n) return;
    float acc = 0.f;
    #pragma unroll 16
    for (int k = 0; k < 128; ++k) acc += xs[r * 128 + k] * Ws[k * 32 + c];
    H[(long)row * 32 + c] = acc;
}

__global__ void mm_32_32(const float* __restrict__ X, const float* __restrict__ W,
                         float* __restrict__ H, int n) {
    __shared__ float Ws[32 * 32];
    __shared__ float xs[8 * 32];
    int t = threadIdx.x;
    for (int i = t; i < 32 * 32; i += 256) Ws[i] = W[i];
    int rbase = blockIdx.x * 8;
    {
        int rr = rbase + (t >> 5);
        xs[t] = (rr < n) ? X[(long)rbase * 32 + t] : 0.f;
    }
    __syncthreads();
    int c = t & 31, r = t >> 5;
    int row = rbase + r;
    if (row >= n) return;
    float acc = 0.f;
    #pragma unroll
    for (int k = 0; k < 32; ++k) acc += xs[r * 32 + k] * Ws[k * 32 + c];
    H[(long)row * 32 + c] = acc;
}

__global__ void mm_32_1(const float* __restrict__ X, const float* __restrict__ W,
                        float* __restrict__ H4, int n) {
    int gid = blockIdx.x * blockDim.x + threadIdx.x;
    int node = gid >> 3, l = gid & 7;
    if (node >= n) return;
    float4 v = *(const float4*)(X + (long)node * 32 + l * 4);
    float s = v.x * W[l * 4] + v.y * W[l * 4 + 1] + v.z * W[l * 4 + 2] + v.w * W[l * 4 + 3];
    s += __shfl_xor(s, 1, 64);
    s += __shfl_xor(s, 2, 64);
    s += __shfl_xor(s, 4, 64);
    if (l == 0) H4[node] = s;
}

// ---------------- edge aggregation (gather) ----------------

__global__ void agg32(const float* __restrict__ H, const int2* __restrict__ eprec,
                      const int* __restrict__ rowptr,
                      const float* __restrict__ snorm, const float* __restrict__ bias,
                      float* __restrict__ OUT, int n) {
    int gid = blockIdx.x * blockDim.x + threadIdx.x;
    int node = gid >> 3, l = gid & 7;
    if (node >= n) return;
    int beg = rowptr[node], end = rowptr[node + 1];
    float ax = 0.f, ay = 0.f, az = 0.f, aw = 0.f;
    int e0 = beg;
    // full batches of 8: unrolled, 8 independent gathers in flight
    for (; e0 + 8 <= end; e0 += 8) {
        int2 ed = eprec[e0 + l];       // coalesced: 8 lanes load 8 consecutive edges
        int ss[8]; float ww[8];
        #pragma unroll
        for (int j = 0; j < 8; ++j) {
            ss[j] = __shfl(ed.x, j, 8);
            ww[j] = __shfl(__int_as_float(ed.y), j, 8);
        }
        float4 hv[8];
        #pragma unroll
        for (int j = 0; j < 8; ++j)
            hv[j] = *(const float4*)(H + (long)ss[j] * 32 + l * 4);
        #pragma unroll
        for (int j = 0; j < 8; ++j) {
            ax += hv[j].x * ww[j]; ay += hv[j].y * ww[j];
            az += hv[j].z * ww[j]; aw += hv[j].w * ww[j];
        }
    }
    // tail
    if (e0 < end) {
        int m = end - e0;
        int2 ed = (l < m) ? eprec[e0 + l] : make_int2(0, 0);
        for (int j = 0; j < m; ++j) {
            int s = __shfl(ed.x, j, 8);
            float w = __shfl(__int_as_float(ed.y), j, 8);
            float4 hv = *(const float4*)(H + (long)s * 32 + l * 4);
            ax += hv.x * w; ay += hv.y * w; az += hv.z * w; aw += hv.w * w;
        }
    }
    float sn = snorm[node];
    float4 hv = *(const float4*)(H + (long)node * 32 + l * 4);
    float4 bv = *(const float4*)(bias + l * 4);
    float4 o;
    o.x = tanhf(ax + hv.x * sn + bv.x);
    o.y = tanhf(ay + hv.y * sn + bv.y);
    o.z = tanhf(az + hv.z * sn + bv.z);
    o.w = tanhf(aw + hv.w * sn + bv.w);
    *(float4*)(OUT + (long)node * 32 + l * 4) = o;
}

__global__ void agg1(const float* __restrict__ H4, const int2* __restrict__ eprec,
                     const int* __restrict__ rowptr,
                     const float* __restrict__ snorm, const float* __restrict__ b4,
                     float* __restrict__ X4, int n) {
    int node = blockIdx.x * blockDim.x + threadIdx.x;
    if (node >= n) return;
    int beg = rowptr[node], end = rowptr[node + 1];
    float acc = 0.f;
    for (int e = beg; e < end; ++e) {
        int2 ed = eprec[e];
        acc += H4[ed.x] * __int_as_float(ed.y);
    }
    X4[node] = tanhf(acc + H4[node] * snorm[node] + b4[0]);
}

// ---------------- topk per graph: 1 wave, LDS-staged argmax-with-marking ----------------

__global__ void graph_start(const int* __restrict__ batch, int* __restrict__ gstart,
                            int n, int B) {
    int i = blockIdx.x * blockDim.x + threadIdx.x;
    if (i >= n) return;
    int b = batch[i];
    int bp = (i == 0) ? -1 : batch[i - 1];
    for (int g = bp + 1; g <= b; ++g) gstart[g] = i;
    if (i == n - 1) {
        for (int g = b + 1; g <= B; ++g) gstart[g] = n;
    }
}

__global__ __launch_bounds__(64) void topk_kernel(const float* __restrict__ keyf,
                                                  const int* __restrict__ gstart,
                                                  int* __restrict__ topi) {
    int g = blockIdx.x;
    int t = threadIdx.x;  // 0..63, single wave
    __shared__ float vals[TKCAP];
    __shared__ int selg[TOPK];
    int beg = gstart[g], end = gstart[g + 1];
    int range = end - beg;
    int lim = range < TKCAP ? range : TKCAP;
    for (int i = t; i < lim; i += 64) vals[i] = keyf[beg + i];
    __syncthreads();
    for (int k = 0; k < TOPK; ++k) {
        float best = -INFINITY;
        int bi = 0x7fffffff;
        // LDS region: strict > keeps lowest index within a lane
        for (int i = t; i < lim; i += 64) {
            float v = vals[i];
            if (v > best) { best = v; bi = i; }
        }
        // overflow region from global (never triggered at range<=TKCAP)
        for (int i = TKCAP + t; i < range; i += 64) {
            int gi = beg + i;
            bool taken = false;
            for (int j = 0; j < k; ++j)
                if (selg[j] == gi) { taken = true; break; }
            if (taken) continue;
            float v = keyf[gi];
            if (v > best || (v == best && i < bi)) { best = v; bi = i; }
        }
        // wave argmax reduce, tie -> lower index
        #pragma unroll
        for (int off = 1; off < 64; off <<= 1) {
            float ov = __shfl_xor(best, off, 64);
            int oi = __shfl_xor(bi, off, 64);
            if (ov > best || (ov == best && oi < bi)) { best = ov; bi = oi; }
        }
        if (t == 0) {
            int gl = (bi == 0x7fffffff) ? -1 : beg + bi;
            selg[k] = gl;
            topi[g * TOPK + k] = gl;
            if (bi != 0x7fffffff && bi < TKCAP) vals[bi] = -INFINITY;
        }
        __syncthreads();
    }
}

// ---------------- head: conv5 -> pool -> conv6 -> fc1 -> fc2 -> log_softmax ----------------

__global__ void head_kernel(const float* __restrict__ x1, const float* __restrict__ x2,
                            const float* __restrict__ x3, const float* __restrict__ x4,
                            const int* __restrict__ topi,
                            const float* __restrict__ w5, const float* __restrict__ b5,
                            const float* __restrict__ w6, const float* __restrict__ b6,
                            const float* __restrict__ fw1, const float* __restrict__ fb1,
                            const float* __restrict__ fw2, const float* __restrict__ fb2,
                            float* __restrict__ out) {
    int b = blockIdx.x;
    int t = threadIdx.x;
    __shared__ float feats[TOPK][97];
    __shared__ float c5[16][30];
    __shared__ float p6[16][15];
    __shared__ float z[352];
    __shared__ float hh[128];
    __shared__ float oo[10];

    for (int idx = t; idx < TOPK * 97; idx += 256) {
        int k = idx / 97, j = idx % 97;
        int node = topi[b * TOPK + k];
        float v = 0.f;
        if (node >= 0) {
            if (j < 32) v = x1[(long)node * 32 + j];
            else if (j < 64) v = x2[(long)node * 32 + (j - 32)];
            else if (j < 96) v = x3[(long)node * 32 + (j - 64)];
            else v = x4[node];
        }
        feats[k][j] = v;
    }
    __syncthreads();

    for (int idx = t; idx < 16 * 30; idx += 256) {
        int oc = idx / 30, k = idx % 30;
        float acc = b5[oc];
        for (int j = 0; j < 97; ++j) acc += w5[oc * 97 + j] * feats[k][j];
        c5[oc][k] = fmaxf(acc, 0.f);
    }
    __syncthreads();

    for (int idx = t; idx < 16 * 15; idx += 256) {
        int oc = idx / 15, k = idx % 15;
        p6[oc][k] = fmaxf(c5[oc][2 * k], c5[oc][2 * k + 1]);
    }
    __syncthreads();

    for (int idx = t; idx < 32 * 11; idx += 256) {
        int oc = idx / 11, tt = idx % 11;
        float acc = b6[oc];
        for (int ic = 0; ic < 16; ++ic)
            for (int j = 0; j < 5; ++j)
                acc += w6[(oc * 16 + ic) * 5 + j] * p6[ic][tt + j];
        z[idx] = fmaxf(acc, 0.f);
    }
    __syncthreads();

    if (t < 128) {
        float acc = fb1[t];
        for (int i = 0; i < 352; ++i) acc += z[i] * fw1[i * 128 + t];
        hh[t] = fmaxf(acc, 0.f);
    }
    __syncthreads();

    if (t < 10) {
        float acc = fb2[t];
        for (int j = 0; j < 128; ++j) acc += hh[j] * fw2[j * 10 + t];
        oo[t] = acc;
    }
    __syncthreads();

    if (t < 10) {
        float m = -INFINITY;
        for (int c = 0; c < 10; ++c) m = fmaxf(m, oo[c]);
        float s = 0.f;
        for (int c = 0; c < 10; ++c) s += expf(oo[c] - m);
        out[b * 10 + t] = oo[t] - m - logf(s);
    }
}

// ---------------- launch ----------------

extern "C" void kernel_launch(void* const* d_in, const int* in_sizes, int n_in,
                              void* d_out, int out_size, void* d_ws, size_t ws_size,
                              hipStream_t stream) {
    const float* x     = (const float*)d_in[0];
    const int*   ei    = (const int*)d_in[1];
    const int*   batch = (const int*)d_in[2];
    const float* W1 = (const float*)d_in[3];
    const float* b1 = (const float*)d_in[4];
    const float* W2 = (const float*)d_in[5];
    const float* b2 = (const float*)d_in[6];
    const float* W3 = (const float*)d_in[7];
    const float* b3 = (const float*)d_in[8];
    const float* W4 = (const float*)d_in[9];
    const float* b4 = (const float*)d_in[10];
    const float* w5 = (const float*)d_in[11];
    const float* b5 = (const float*)d_in[12];
    const float* w6 = (const float*)d_in[13];
    const float* b6 = (const float*)d_in[14];
    const float* fw1 = (const float*)d_in[15];
    const float* fb1 = (const float*)d_in[16];
    const float* fw2 = (const float*)d_in[17];
    const float* fb2 = (const float*)d_in[18];

    const int N = in_sizes[0] / 128;
    const int E = in_sizes[1] / 2;
    const int* src = ei;
    const int* dst = ei + E;

    char* w = (char*)d_ws;
    size_t off = 0;
    auto alloc = [&](size_t bytes) -> void* {
        void* p = w + off;
        off = (off + bytes + 255) & ~(size_t)255;
        return p;
    };

    int*   cnt    = (int*)alloc((size_t)N * 4);
    int*   rowptr = (int*)alloc((size_t)(N + 1) * 4);
    int*   bsum   = (int*)alloc(4096 * 4);
    int*   gcur   = (int*)alloc(NBMAX * 4);
    int*   btot   = (int*)alloc(NBMAX * 4);
    int*   bbase  = (int*)alloc(NBMAX * 4);
    int*   fcur   = (int*)alloc(NFMAX * 4);
    float* dinv   = (float*)alloc((size_t)N * 4);
    float* snorm  = (float*)alloc((size_t)N * 4);
    int2*  eprec  = (int2*)alloc((size_t)E * 8);
    float* hbuf   = (float*)alloc((size_t)N * 32 * 4);   // aliased as scratch
    float* x1     = (float*)alloc((size_t)N * 32 * 4);   // aliased as scratch2
    float* x2     = (float*)alloc((size_t)N * 32 * 4);
    float* x3     = (float*)alloc((size_t)N * 32 * 4);
    float* h4     = (float*)alloc((size_t)N * 4);
    float* x4     = (float*)alloc((size_t)N * 4);
    int*   gstart = (int*)alloc((size_t)(NGRAPH + 1) * 4);
    int*   topi   = (int*)alloc((size_t)NGRAPH * TOPK * 4);

    int2* scratch  = (int2*)hbuf;  // live: bin_edges .. bin2 (before mm_128_32)
    int2* scratch2 = (int2*)x1;    // live: bin2 .. scatter_sort (before layer-1 agg32)

    hipMemsetAsync(gcur, 0, NBMAX * 4, stream);
    hipMemsetAsync(btot, 0, NBMAX * 4, stream);
    hipMemsetAsync(fcur, 0, NFMAX * 4, stream);

    const int NB = (N + (1 << BSHIFT) - 1) >> BSHIFT;
    const int NF = (N + (1 << FSHIFT) - 1) >> FSHIFT;
    const int EB = (E + 2047) / 2048;

    bhist<<<EB, TPB, 0, stream>>>(src, dst, btot, E);
    bucket_scan<<<1, NBMAX, 0, stream>>>(btot, bbase, NB);
    bin_edges<<<EB, TPB, 0, stream>>>(src, dst, bbase, gcur, scratch, E);
    bucket_count<<<NB, TPB, 0, stream>>>(scratch, bbase, btot, cnt, dinv, snorm, N);

    int nb = (N + 1023) / 1024;
    scan1<<<nb, 256, 0, stream>>>(cnt, rowptr, bsum, N);
    scan2<<<1, 256, 0, stream>>>(bsum, nb);
    scan3<<<(N + TPB - 1) / TPB, TPB, 0, stream>>>(rowptr, bsum, N, nb);

    bin2<<<(E + 8191) / 8192, TPB, 0, stream>>>(scratch, rowptr, fcur, scratch2, N, E);
    scatter_sort<<<NF, 256, 0, stream>>>(scratch2, rowptr, dinv, eprec, N);

    // layer 1
    mm_128_32<<<(N + 7) / 8, 256, 0, stream>>>(x, W1, hbuf, N);
    agg32<<<((size_t)N * 8 + TPB - 1) / TPB, TPB, 0, stream>>>(hbuf, eprec, rowptr,
                                                               snorm, b1, x1, N);
    // layer 2
    mm_32_32<<<(N + 7) / 8, 256, 0, stream>>>(x1, W2, hbuf, N);
    agg32<<<((size_t)N * 8 + TPB - 1) / TPB, TPB, 0, stream>>>(hbuf, eprec, rowptr,
                                                               snorm, b2, x2, N);
    // layer 3
    mm_32_32<<<(N + 7) / 8, 256, 0, stream>>>(x2, W3, hbuf, N);
    agg32<<<((size_t)N * 8 + TPB - 1) / TPB, TPB, 0, stream>>>(hbuf, eprec, rowptr,
                                                               snorm, b3, x3, N);
    // layer 4
    mm_32_1<<<((size_t)N * 8 + TPB - 1) / TPB, TPB, 0, stream>>>(x3, W4, h4, N);
    agg1<<<(N + TPB - 1) / TPB, TPB, 0, stream>>>(h4, eprec, rowptr, snorm, b4, x4, N);

    // topk + head
    graph_start<<<(N + TPB - 1) / TPB, TPB, 0, stream>>>(batch, gstart, N, NGRAPH);
    topk_kernel<<<NGRAPH, 64, 0, stream>>>(x4, gstart, topi);
    head_kernel<<<NGRAPH, 256, 0, stream>>>(x1, x2, x3, x4, topi, w5, b5, w6, b6,
                                            fw1, fb1, fw2, fb2, (float*)d_out);
}

// Round 9
// 600.120 us; speedup vs baseline: 1.4919x; 1.0986x over previous
//
#include <hip/hip_runtime.h>
#include <math.h>

#define TPB 256
#define TOPK 30
#define NGRAPH 128
#define TKCAP 4096
#define BSHIFT 11
#define NBMAX 128
#define FSHIFT 8
#define NFMAX 800
#define FCAP 4608

// ---------------- CSR build (bucket-based, no random global atomics) ----------------

__global__ void bhist(const int* __restrict__ src, const int* __restrict__ dst,
                      int* __restrict__ btot, int E) {
    __shared__ int bcnt[NBMAX];
    int t = threadIdx.x;
    int base = blockIdx.x * 2048;
    int lim = E - base; if (lim > 2048) lim = 2048;
    for (int i = t; i < NBMAX; i += 256) bcnt[i] = 0;
    __syncthreads();
    for (int i = t; i < lim; i += 256) {
        int s = src[base + i], d = dst[base + i];
        if (s != d) atomicAdd(&bcnt[d >> BSHIFT], 1);
    }
    __syncthreads();
    for (int i = t; i < NBMAX; i += 256)
        if (bcnt[i] > 0) atomicAdd(&btot[i], bcnt[i]);
}

__global__ void bucket_scan(const int* __restrict__ btot, int* __restrict__ bbase,
                            int nbuckets) {
    __shared__ int ls[NBMAX];
    int t = threadIdx.x;
    int v = (t < nbuckets) ? btot[t] : 0;
    ls[t] = v;
    __syncthreads();
    for (int o = 1; o < NBMAX; o <<= 1) {
        int x = 0;
        if (t >= o) x = ls[t - o];
        __syncthreads();
        ls[t] += x;
        __syncthreads();
    }
    if (t < nbuckets) bbase[t] = ls[t] - v;
}

__global__ void bin_edges(const int* __restrict__ src, const int* __restrict__ dst,
                          const int* __restrict__ bbase_g, int* __restrict__ gcur,
                          int2* __restrict__ scratch, int E) {
    __shared__ int2 eds[2048];
    __shared__ int bcnt[NBMAX], bbase[NBMAX], boff[NBMAX];
    int t = threadIdx.x;
    int base = blockIdx.x * 2048;
    int lim = E - base; if (lim > 2048) lim = 2048;
    for (int i = t; i < NBMAX; i += 256) { bcnt[i] = 0; boff[i] = 0; }
    __syncthreads();
    for (int i = t; i < lim; i += 256) {
        int s = src[base + i], d = dst[base + i];
        if (s == d) d = -1;                  // drop self-loops
        eds[i] = make_int2(s, d);
        if (d >= 0) atomicAdd(&bcnt[d >> BSHIFT], 1);
    }
    __syncthreads();
    for (int i = t; i < NBMAX; i += 256) {
        if (bcnt[i] > 0)
            bbase[i] = bbase_g[i] + atomicAdd(&gcur[i], bcnt[i]);
    }
    __syncthreads();
    for (int i = t; i < lim; i += 256) {
        int2 ed = eds[i];
        if (ed.y >= 0) {
            int b = ed.y >> BSHIFT;
            int pos = bbase[b] + atomicAdd(&boff[b], 1);
            scratch[pos] = ed;
        }
    }
}

__global__ void bucket_count(const int2* __restrict__ scratch,
                             const int* __restrict__ bbase, const int* __restrict__ btot,
                             int* __restrict__ cnt, float* __restrict__ dinv,
                             float* __restrict__ snorm, int N) {
    __shared__ int hist[1 << BSHIFT];
    int b = blockIdx.x, t = threadIdx.x;
    int nlo = b << BSHIFT;
    int nn = N - nlo; if (nn > (1 << BSHIFT)) nn = 1 << BSHIFT;
    for (int i = t; i < (1 << BSHIFT); i += 256) hist[i] = 0;
    __syncthreads();
    int lo = bbase[b], hi = lo + btot[b];
    for (int e = lo + t; e < hi; e += 256)
        atomicAdd(&hist[scratch[e].y - nlo], 1);
    __syncthreads();
    for (int i = t; i < nn; i += 256) {
        int c = hist[i];
        cnt[nlo + i] = c;
        float deg = (float)c + 1.0f;
        dinv[nlo + i] = 1.0f / sqrtf(deg);
        snorm[nlo + i] = 1.0f / deg;
    }
}

// exclusive scan, 1024 elems per block
__global__ void scan1(const int* __restrict__ cnt, int* __restrict__ outp,
                      int* __restrict__ bsum, int n) {
    __shared__ int ls[256];
    int t = threadIdx.x;
    int base = blockIdx.x * 1024;
    int v[4], ex[4];
    int run = 0;
    #pragma unroll
    for (int j = 0; j < 4; ++j) {
        int i = base + t * 4 + j;
        v[j] = (i < n) ? cnt[i] : 0;
        ex[j] = run;
        run += v[j];
    }
    ls[t] = run;
    __syncthreads();
    for (int o2 = 1; o2 < 256; o2 <<= 1) {
        int xv = 0;
        if (t >= o2) xv = ls[t - o2];
        __syncthreads();
        ls[t] += xv;
        __syncthreads();
    }
    int tbase = ls[t] - run;   // exclusive base for this thread
    #pragma unroll
    for (int j = 0; j < 4; ++j) {
        int i = base + t * 4 + j;
        if (i < n) outp[i] = tbase + ex[j];
    }
    if (t == 255) bsum[blockIdx.x] = ls[255];
}

__global__ void scan2(int* __restrict__ bsum, int nb) {
    __shared__ int ls[256];
    int t = threadIdx.x;
    int v = (t < nb) ? bsum[t] : 0;
    ls[t] = v;
    __syncthreads();
    for (int o2 = 1; o2 < 256; o2 <<= 1) {
        int xv = 0;
        if (t >= o2) xv = ls[t - o2];
        __syncthreads();
        ls[t] += xv;
        __syncthreads();
    }
    if (t < nb) bsum[t] = ls[t] - v;     // exclusive
    if (t == 255) bsum[nb] = ls[255];    // total
}

__global__ void scan3(int* __restrict__ rowptr, const int* __restrict__ bsum, int n, int nb) {
    int i = blockIdx.x * blockDim.x + threadIdx.x;
    if (i < n) rowptr[i] += bsum[i >> 10];
    if (i == 0) rowptr[n] = bsum[nb];
}

__global__ void bin2(const int2* __restrict__ scratch, const int* __restrict__ rowptr,
                     int* __restrict__ fcur, int2* __restrict__ scratch2, int N, int E) {
    __shared__ int fcnt[NFMAX], fbase[NFMAX], foff[NFMAX];
    int t = threadIdx.x;
    int En = rowptr[N];
    int base = blockIdx.x * 8192;
    if (base >= En) return;
    int lim = En - base; if (lim > 8192) lim = 8192;
    for (int i = t; i < NFMAX; i += 256) { fcnt[i] = 0; foff[i] = 0; }
    __syncthreads();
    for (int i = t; i < lim; i += 256) {
        int d = scratch[base + i].y;
        atomicAdd(&fcnt[d >> FSHIFT], 1);
    }
    __syncthreads();
    for (int fi = t; fi < NFMAX; fi += 256) {
        if (fcnt[fi] > 0)
            fbase[fi] = rowptr[fi << FSHIFT] + atomicAdd(&fcur[fi], fcnt[fi]);
    }
    __syncthreads();
    for (int i = t; i < lim; i += 256) {
        int2 ed = scratch[base + i];
        int fi = ed.y >> FSHIFT;
        int pos = fbase[fi] + atomicAdd(&foff[fi], 1);
        scratch2[pos] = ed;
    }
}

__global__ __launch_bounds__(256) void scatter_sort(const int2* __restrict__ scratch2,
                                                    const int* __restrict__ rowptr,
                                                    const float* __restrict__ dinv,
                                                    int2* __restrict__ eprec, int N) {
    __shared__ int srcA[FCAP], dstA[FCAP], inv[FCAP];
    __shared__ int hist[1 << FSHIFT];
    __shared__ int hcur[1 << FSHIFT];
    int f = blockIdx.x, t = threadIdx.x;
    int nlo = f << FSHIFT;
    int nhi = nlo + (1 << FSHIFT); if (nhi > N) nhi = N;
    int lo = rowptr[nlo], hi = rowptr[nhi];
    int span = hi - lo;
    for (int i = t; i < (1 << FSHIFT); i += 256) hist[i] = 0;
    __syncthreads();
    if (span <= FCAP) {
        for (int i = t; i < span; i += 256) {
            int2 ed = scratch2[lo + i];
            srcA[i] = ed.x; dstA[i] = ed.y;
            atomicAdd(&hist[ed.y - nlo], 1);
        }
        __syncthreads();
        int v = hist[t];
        hcur[t] = v;
        __syncthreads();
        for (int o = 1; o < 256; o <<= 1) {
            int x = (t >= o) ? hcur[t - o] : 0;
            __syncthreads();
            hcur[t] += x;
            __syncthreads();
        }
        int excl = hcur[t] - v;
        __syncthreads();
        hcur[t] = excl;
        __syncthreads();
        for (int i = t; i < span; i += 256) {
            int slot = atomicAdd(&hcur[dstA[i] - nlo], 1);
            inv[slot] = i;
        }
        __syncthreads();
        for (int p = t; p < span; p += 256) {
            int i = inv[p];
            int s = srcA[i], d = dstA[i];
            eprec[lo + p] = make_int2(s, __float_as_int(dinv[s] * dinv[d]));
        }
    } else {
        for (int e = lo + t; e < hi; e += 256) {
            int2 ed = scratch2[e];
            int d = ed.y;
            int p = rowptr[d] + atomicAdd(&hist[d - nlo], 1);
            eprec[p] = make_int2(ed.x, __float_as_int(dinv[ed.x] * dinv[d]));
        }
    }
}

// ---------------- GEMMs (register-tiled: 4 cols/thread, b128 LDS reads) ----------------

// 32 rows/block; thread t: row = t>>3, cols = (t&7)*4 .. +3.
// Inner loop: 1 xs b128 (4 k) + 4 Ws b128 -> 16 FMA; 5 LDS ops / 16 FMA.
// k-order identical to naive loop -> bitwise-same accumulation.
__global__ void mm_128_32(const float* __restrict__ X, const float* __restrict__ W,
                          float* __restrict__ H, int n) {
    __shared__ float Ws[128 * 32];
    __shared__ float xs[32 * 128];
    int t = threadIdx.x;
    int rbase = blockIdx.x * 32;
    #pragma unroll
    for (int j = 0; j < 4; ++j) {
        int idx = t + 256 * j;           // float4 index, 1024 total
        *(float4*)(Ws + idx * 4) = *(const float4*)(W + idx * 4);
        int row = rbase + (idx >> 5);
        float4 v = make_float4(0.f, 0.f, 0.f, 0.f);
        if (row < n) v = *(const float4*)(X + (long)rbase * 128 + idx * 4);
        *(float4*)(xs + idx * 4) = v;
    }
    __syncthreads();
    int c4 = (t & 7) * 4, r = t >> 3;
    int row = rbase + r;
    if (row >= n) return;
    float ac0 = 0.f, ac1 = 0.f, ac2 = 0.f, ac3 = 0.f;
    #pragma unroll 8
    for (int k0 = 0; k0 < 128; k0 += 4) {
        float4 xv = *(const float4*)(xs + r * 128 + k0);
        #pragma unroll
        for (int j = 0; j < 4; ++j) {
            float xj = (j == 0) ? xv.x : (j == 1) ? xv.y : (j == 2) ? xv.z : xv.w;
            float4 wv = *(const float4*)(Ws + (k0 + j) * 32 + c4);
            ac0 += xj * wv.x; ac1 += xj * wv.y; ac2 += xj * wv.z; ac3 += xj * wv.w;
        }
    }
    *(float4*)(H + (long)row * 32 + c4) = make_float4(ac0, ac1, ac2, ac3);
}

__global__ void mm_32_32(const float* __restrict__ X, const float* __restrict__ W,
                         float* __restrict__ H, int n) {
    __shared__ float Ws[32 * 32];
    __shared__ float xs[32 * 32];
    int t = threadIdx.x;
    int rbase = blockIdx.x * 32;
    {
        *(float4*)(Ws + t * 4) = *(const float4*)(W + t * 4);
        int row = rbase + (t >> 3);
        float4 v = make_float4(0.f, 0.f, 0.f, 0.f);
        if (row < n) v = *(const float4*)(X + (long)rbase * 32 + t * 4);
        *(float4*)(xs + t * 4) = v;
    }
    __syncthreads();
    int c4 = (t & 7) * 4, r = t >> 3;
    int row = rbase + r;
    if (row >= n) return;
    float ac0 = 0.f, ac1 = 0.f, ac2 = 0.f, ac3 = 0.f;
    #pragma unroll
    for (int k0 = 0; k0 < 32; k0 += 4) {
        float4 xv = *(const float4*)(xs + r * 32 + k0);
        #pragma unroll
        for (int j = 0; j < 4; ++j) {
            float xj = (j == 0) ? xv.x : (j == 1) ? xv.y : (j == 2) ? xv.z : xv.w;
            float4 wv = *(const float4*)(Ws + (k0 + j) * 32 + c4);
            ac0 += xj * wv.x; ac1 += xj * wv.y; ac2 += xj * wv.z; ac3 += xj * wv.w;
        }
    }
    *(float4*)(H + (long)row * 32 + c4) = make_float4(ac0, ac1, ac2, ac3);
}

__global__ void mm_32_1(const float* __restrict__ X, const float* __restrict__ W,
                        float* __restrict__ H4, int n) {
    int gid = blockIdx.x * blockDim.x + threadIdx.x;
    int node = gid >> 3, l = gid & 7;
    if (node >= n) return;
    float4 v = *(const float4*)(X + (long)node * 32 + l * 4);
    float s = v.x * W[l * 4] + v.y * W[l * 4 + 1] + v.z * W[l * 4 + 2] + v.w * W[l * 4 + 3];
    s += __shfl_xor(s, 1, 64);
    s += __shfl_xor(s, 2, 64);
    s += __shfl_xor(s, 4, 64);
    if (l == 0) H4[node] = s;
}

// ---------------- edge aggregation (gather) ----------------

__global__ void agg32(const float* __restrict__ H, const int2* __restrict__ eprec,
                      const int* __restrict__ rowptr,
                      const float* __restrict__ snorm, const float* __restrict__ bias,
                      float* __restrict__ OUT, int n) {
    int gid = blockIdx.x * blockDim.x + threadIdx.x;
    int node = gid >> 3, l = gid & 7;
    if (node >= n) return;
    int beg = rowptr[node], end = rowptr[node + 1];
    float ax = 0.f, ay = 0.f, az = 0.f, aw = 0.f;
    int e0 = beg;
    for (; e0 + 8 <= end; e0 += 8) {
        int2 ed = eprec[e0 + l];
        int ss[8]; float ww[8];
        #pragma unroll
        for (int j = 0; j < 8; ++j) {
            ss[j] = __shfl(ed.x, j, 8);
            ww[j] = __shfl(__int_as_float(ed.y), j, 8);
        }
        float4 hv[8];
        #pragma unroll
        for (int j = 0; j < 8; ++j)
            hv[j] = *(const float4*)(H + (long)ss[j] * 32 + l * 4);
        #pragma unroll
        for (int j = 0; j < 8; ++j) {
            ax += hv[j].x * ww[j]; ay += hv[j].y * ww[j];
            az += hv[j].z * ww[j]; aw += hv[j].w * ww[j];
        }
    }
    if (e0 < end) {
        int m = end - e0;
        int2 ed = (l < m) ? eprec[e0 + l] : make_int2(0, 0);
        for (int j = 0; j < m; ++j) {
            int s = __shfl(ed.x, j, 8);
            float w = __shfl(__int_as_float(ed.y), j, 8);
            float4 hv = *(const float4*)(H + (long)s * 32 + l * 4);
            ax += hv.x * w; ay += hv.y * w; az += hv.z * w; aw += hv.w * w;
        }
    }
    float sn = snorm[node];
    float4 hv = *(const float4*)(H + (long)node * 32 + l * 4);
    float4 bv = *(const float4*)(bias + l * 4);
    float4 o;
    o.x = tanhf(ax + hv.x * sn + bv.x);
    o.y = tanhf(ay + hv.y * sn + bv.y);
    o.z = tanhf(az + hv.z * sn + bv.z);
    o.w = tanhf(aw + hv.w * sn + bv.w);
    *(float4*)(OUT + (long)node * 32 + l * 4) = o;
}

__global__ void agg1(const float* __restrict__ H4, const int2* __restrict__ eprec,
                     const int* __restrict__ rowptr,
                     const float* __restrict__ snorm, const float* __restrict__ b4,
                     float* __restrict__ X4, int n) {
    int node = blockIdx.x * blockDim.x + threadIdx.x;
    if (node >= n) return;
    int beg = rowptr[node], end = rowptr[node + 1];
    float acc = 0.f;
    for (int e = beg; e < end; ++e) {
        int2 ed = eprec[e];
        acc += H4[ed.x] * __int_as_float(ed.y);
    }
    X4[node] = tanhf(acc + H4[node] * snorm[node] + b4[0]);
}

// ---------------- topk per graph: 1 wave, LDS-staged argmax-with-marking ----------------

__global__ void graph_start(const int* __restrict__ batch, int* __restrict__ gstart,
                            int n, int B) {
    int i = blockIdx.x * blockDim.x + threadIdx.x;
    if (i >= n) return;
    int b = batch[i];
    int bp = (i == 0) ? -1 : batch[i - 1];
    for (int g = bp + 1; g <= b; ++g) gstart[g] = i;
    if (i == n - 1) {
        for (int g = b + 1; g <= B; ++g) gstart[g] = n;
    }
}

__global__ __launch_bounds__(64) void topk_kernel(const float* __restrict__ keyf,
                                                  const int* __restrict__ gstart,
                                                  int* __restrict__ topi) {
    int g = blockIdx.x;
    int t = threadIdx.x;  // 0..63, single wave
    __shared__ float vals[TKCAP];
    __shared__ int selg[TOPK];
    int beg = gstart[g], end = gstart[g + 1];
    int range = end - beg;
    int lim = range < TKCAP ? range : TKCAP;
    for (int i = t; i < lim; i += 64) vals[i] = keyf[beg + i];
    __syncthreads();
    for (int k = 0; k < TOPK; ++k) {
        float best = -INFINITY;
        int bi = 0x7fffffff;
        for (int i = t; i < lim; i += 64) {
            float v = vals[i];
            if (v > best) { best = v; bi = i; }
        }
        for (int i = TKCAP + t; i < range; i += 64) {
            int gi = beg + i;
            bool taken = false;
            for (int j = 0; j < k; ++j)
                if (selg[j] == gi) { taken = true; break; }
            if (taken) continue;
            float v = keyf[gi];
            if (v > best || (v == best && i < bi)) { best = v; bi = i; }
        }
        #pragma unroll
        for (int off = 1; off < 64; off <<= 1) {
            float ov = __shfl_xor(best, off, 64);
            int oi = __shfl_xor(bi, off, 64);
            if (ov > best || (ov == best && oi < bi)) { best = ov; bi = oi; }
        }
        if (t == 0) {
            int gl = (bi == 0x7fffffff) ? -1 : beg + bi;
            selg[k] = gl;
            topi[g * TOPK + k] = gl;
            if (bi != 0x7fffffff && bi < TKCAP) vals[bi] = -INFINITY;
        }
        __syncthreads();
    }
}

// ---------------- head: conv5 -> pool -> conv6 -> fc1 -> fc2 -> log_softmax ----------------

__global__ void head_kernel(const float* __restrict__ x1, const float* __restrict__ x2,
                            const float* __restrict__ x3, const float* __restrict__ x4,
                            const int* __restrict__ topi,
                            const float* __restrict__ w5, const float* __restrict__ b5,
                            const float* __restrict__ w6, const float* __restrict__ b6,
                            const float* __restrict__ fw1, const float* __restrict__ fb1,
                            const float* __restrict__ fw2, const float* __restrict__ fb2,
                            float* __restrict__ out) {
    int b = blockIdx.x;
    int t = threadIdx.x;
    __shared__ float feats[TOPK][97];
    __shared__ float c5[16][30];
    __shared__ float p6[16][15];
    __shared__ float z[352];
    __shared__ float hh[128];
    __shared__ float oo[10];

    for (int idx = t; idx < TOPK * 97; idx += 256) {
        int k = idx / 97, j = idx % 97;
        int node = topi[b * TOPK + k];
        float v = 0.f;
        if (node >= 0) {
            if (j < 32) v = x1[(long)node * 32 + j];
            else if (j < 64) v = x2[(long)node * 32 + (j - 32)];
            else if (j < 96) v = x3[(long)node * 32 + (j - 64)];
            else v = x4[node];
        }
        feats[k][j] = v;
    }
    __syncthreads();

    for (int idx = t; idx < 16 * 30; idx += 256) {
        int oc = idx / 30, k = idx % 30;
        float acc = b5[oc];
        for (int j = 0; j < 97; ++j) acc += w5[oc * 97 + j] * feats[k][j];
        c5[oc][k] = fmaxf(acc, 0.f);
    }
    __syncthreads();

    for (int idx = t; idx < 16 * 15; idx += 256) {
        int oc = idx / 15, k = idx % 15;
        p6[oc][k] = fmaxf(c5[oc][2 * k], c5[oc][2 * k + 1]);
    }
    __syncthreads();

    for (int idx = t; idx < 32 * 11; idx += 256) {
        int oc = idx / 11, tt = idx % 11;
        float acc = b6[oc];
        for (int ic = 0; ic < 16; ++ic)
            for (int j = 0; j < 5; ++j)
                acc += w6[(oc * 16 + ic) * 5 + j] * p6[ic][tt + j];
        z[idx] = fmaxf(acc, 0.f);
    }
    __syncthreads();

    if (t < 128) {
        float acc = fb1[t];
        for (int i = 0; i < 352; ++i) acc += z[i] * fw1[i * 128 + t];
        hh[t] = fmaxf(acc, 0.f);
    }
    __syncthreads();

    if (t < 10) {
        float acc = fb2[t];
        for (int j = 0; j < 128; ++j) acc += hh[j] * fw2[j * 10 + t];
        oo[t] = acc;
    }
    __syncthreads();

    if (t < 10) {
        float m = -INFINITY;
        for (int c = 0; c < 10; ++c) m = fmaxf(m, oo[c]);
        float s = 0.f;
        for (int c = 0; c < 10; ++c) s += expf(oo[c] - m);
        out[b * 10 + t] = oo[t] - m - logf(s);
    }
}

// ---------------- launch ----------------

extern "C" void kernel_launch(void* const* d_in, const int* in_sizes, int n_in,
                              void* d_out, int out_size, void* d_ws, size_t ws_size,
                              hipStream_t stream) {
    const float* x     = (const float*)d_in[0];
    const int*   ei    = (const int*)d_in[1];
    const int*   batch = (const int*)d_in[2];
    const float* W1 = (const float*)d_in[3];
    const float* b1 = (const float*)d_in[4];
    const float* W2 = (const float*)d_in[5];
    const float* b2 = (const float*)d_in[6];
    const float* W3 = (const float*)d_in[7];
    const float* b3 = (const float*)d_in[8];
    const float* W4 = (const float*)d_in[9];
    const float* b4 = (const float*)d_in[10];
    const float* w5 = (const float*)d_in[11];
    const float* b5 = (const float*)d_in[12];
    const float* w6 = (const float*)d_in[13];
    const float* b6 = (const float*)d_in[14];
    const float* fw1 = (const float*)d_in[15];
    const float* fb1 = (const float*)d_in[16];
    const float* fw2 = (const float*)d_in[17];
    const float* fb2 = (const float*)d_in[18];

    const int N = in_sizes[0] / 128;
    const int E = in_sizes[1] / 2;
    const int* src = ei;
    const int* dst = ei + E;

    char* w = (char*)d_ws;
    size_t off = 0;
    auto alloc = [&](size_t bytes) -> void* {
        void* p = w + off;
        off = (off + bytes + 255) & ~(size_t)255;
        return p;
    };

    int*   cnt    = (int*)alloc((size_t)N * 4);
    int*   rowptr = (int*)alloc((size_t)(N + 1) * 4);
    int*   bsum   = (int*)alloc(4096 * 4);
    int*   gcur   = (int*)alloc(NBMAX * 4);
    int*   btot   = (int*)alloc(NBMAX * 4);
    int*   bbase  = (int*)alloc(NBMAX * 4);
    int*   fcur   = (int*)alloc(NFMAX * 4);
    float* dinv   = (float*)alloc((size_t)N * 4);
    float* snorm  = (float*)alloc((size_t)N * 4);
    int2*  eprec  = (int2*)alloc((size_t)E * 8);
    float* hbuf   = (float*)alloc((size_t)N * 32 * 4);   // aliased as scratch
    float* x1     = (float*)alloc((size_t)N * 32 * 4);   // aliased as scratch2
    float* x2     = (float*)alloc((size_t)N * 32 * 4);
    float* x3     = (float*)alloc((size_t)N * 32 * 4);
    float* h4     = (float*)alloc((size_t)N * 4);
    float* x4     = (float*)alloc((size_t)N * 4);
    int*   gstart = (int*)alloc((size_t)(NGRAPH + 1) * 4);
    int*   topi   = (int*)alloc((size_t)NGRAPH * TOPK * 4);

    int2* scratch  = (int2*)hbuf;
    int2* scratch2 = (int2*)x1;

    hipMemsetAsync(gcur, 0, NBMAX * 4, stream);
    hipMemsetAsync(btot, 0, NBMAX * 4, stream);
    hipMemsetAsync(fcur, 0, NFMAX * 4, stream);

    const int NB = (N + (1 << BSHIFT) - 1) >> BSHIFT;
    const int NF = (N + (1 << FSHIFT) - 1) >> FSHIFT;
    const int EB = (E + 2047) / 2048;

    bhist<<<EB, TPB, 0, stream>>>(src, dst, btot, E);
    bucket_scan<<<1, NBMAX, 0, stream>>>(btot, bbase, NB);
    bin_edges<<<EB, TPB, 0, stream>>>(src, dst, bbase, gcur, scratch, E);
    bucket_count<<<NB, TPB, 0, stream>>>(scratch, bbase, btot, cnt, dinv, snorm, N);

    int nb = (N + 1023) / 1024;
    scan1<<<nb, 256, 0, stream>>>(cnt, rowptr, bsum, N);
    scan2<<<1, 256, 0, stream>>>(bsum, nb);
    scan3<<<(N + TPB - 1) / TPB, TPB, 0, stream>>>(rowptr, bsum, N, nb);

    bin2<<<(E + 8191) / 8192, TPB, 0, stream>>>(scratch, rowptr, fcur, scratch2, N, E);
    scatter_sort<<<NF, 256, 0, stream>>>(scratch2, rowptr, dinv, eprec, N);

    // layer 1
    mm_128_32<<<(N + 31) / 32, 256, 0, stream>>>(x, W1, hbuf, N);
    agg32<<<((size_t)N * 8 + TPB - 1) / TPB, TPB, 0, stream>>>(hbuf, eprec, rowptr,
                                                               snorm, b1, x1, N);
    // layer 2
    mm_32_32<<<(N + 31) / 32, 256, 0, stream>>>(x1, W2, hbuf, N);
    agg32<<<((size_t)N * 8 + TPB - 1) / TPB, TPB, 0, stream>>>(hbuf, eprec, rowptr,
                                                               snorm, b2, x2, N);
    // layer 3
    mm_32_32<<<(N + 31) / 32, 256, 0, stream>>>(x2, W3, hbuf, N);
    agg32<<<((size_t)N * 8 + TPB - 1) / TPB, TPB, 0, stream>>>(hbuf, eprec, rowptr,
                                                               snorm, b3, x3, N);
    // layer 4
    mm_32_1<<<((size_t)N * 8 + TPB - 1) / TPB, TPB, 0, stream>>>(x3, W4, h4, N);
    agg1<<<(N + TPB - 1) / TPB, TPB, 0, stream>>>(h4, eprec, rowptr, snorm, b4, x4, N);

    // topk + head
    graph_start<<<(N + TPB - 1) / TPB, TPB, 0, stream>>>(batch, gstart, N, NGRAPH);
    topk_kernel<<<NGRAPH, 64, 0, stream>>>(x4, gstart, topi);
    head_kernel<<<NGRAPH, 256, 0, stream>>>(x1, x2, x3, x4, topi, w5, b5, w6, b6,
                                            fw1, fb1, fw2, fb2, (float*)d_out);
}

// Round 10
// 563.035 us; speedup vs baseline: 1.5901x; 1.0659x over previous
//
#include <hip/hip_runtime.h>
#include <math.h>

#define TPB 256
#define TOPK 30
#define NGRAPH 128
#define TKCAP 4096
#define BSHIFT 11
#define NBMAX 128
#define FSHIFT 8
#define NFMAX 800
#define FCAP 4608

// ---------------- CSR build (bucket-based, no random global atomics) ----------------

__global__ void bhist(const int* __restrict__ src, const int* __restrict__ dst,
                      int* __restrict__ btot, int E) {
    __shared__ int bcnt[NBMAX];
    int t = threadIdx.x;
    int base = blockIdx.x * 2048;
    int lim = E - base; if (lim > 2048) lim = 2048;
    for (int i = t; i < NBMAX; i += 256) bcnt[i] = 0;
    __syncthreads();
    for (int i = t; i < lim; i += 256) {
        int s = src[base + i], d = dst[base + i];
        if (s != d) atomicAdd(&bcnt[d >> BSHIFT], 1);
    }
    __syncthreads();
    for (int i = t; i < NBMAX; i += 256)
        if (bcnt[i] > 0) atomicAdd(&btot[i], bcnt[i]);
}

__global__ void bucket_scan(const int* __restrict__ btot, int* __restrict__ bbase,
                            int nbuckets) {
    __shared__ int ls[NBMAX];
    int t = threadIdx.x;
    int v = (t < nbuckets) ? btot[t] : 0;
    ls[t] = v;
    __syncthreads();
    for (int o = 1; o < NBMAX; o <<= 1) {
        int x = 0;
        if (t >= o) x = ls[t - o];
        __syncthreads();
        ls[t] += x;
        __syncthreads();
    }
    if (t < nbuckets) bbase[t] = ls[t] - v;
}

__global__ void bin_edges(const int* __restrict__ src, const int* __restrict__ dst,
                          const int* __restrict__ bbase_g, int* __restrict__ gcur,
                          int2* __restrict__ scratch, int E) {
    __shared__ int2 eds[2048];
    __shared__ int bcnt[NBMAX], bbase[NBMAX], boff[NBMAX];
    int t = threadIdx.x;
    int base = blockIdx.x * 2048;
    int lim = E - base; if (lim > 2048) lim = 2048;
    for (int i = t; i < NBMAX; i += 256) { bcnt[i] = 0; boff[i] = 0; }
    __syncthreads();
    for (int i = t; i < lim; i += 256) {
        int s = src[base + i], d = dst[base + i];
        if (s == d) d = -1;                  // drop self-loops
        eds[i] = make_int2(s, d);
        if (d >= 0) atomicAdd(&bcnt[d >> BSHIFT], 1);
    }
    __syncthreads();
    for (int i = t; i < NBMAX; i += 256) {
        if (bcnt[i] > 0)
            bbase[i] = bbase_g[i] + atomicAdd(&gcur[i], bcnt[i]);
    }
    __syncthreads();
    for (int i = t; i < lim; i += 256) {
        int2 ed = eds[i];
        if (ed.y >= 0) {
            int b = ed.y >> BSHIFT;
            int pos = bbase[b] + atomicAdd(&boff[b], 1);
            scratch[pos] = ed;
        }
    }
}

__global__ void bucket_count(const int2* __restrict__ scratch,
                             const int* __restrict__ bbase, const int* __restrict__ btot,
                             int* __restrict__ cnt, float* __restrict__ dinv,
                             float* __restrict__ snorm, int N) {
    __shared__ int hist[1 << BSHIFT];
    int b = blockIdx.x, t = threadIdx.x;
    int nlo = b << BSHIFT;
    int nn = N - nlo; if (nn > (1 << BSHIFT)) nn = 1 << BSHIFT;
    for (int i = t; i < (1 << BSHIFT); i += 256) hist[i] = 0;
    __syncthreads();
    int lo = bbase[b], hi = lo + btot[b];
    for (int e = lo + t; e < hi; e += 256)
        atomicAdd(&hist[scratch[e].y - nlo], 1);
    __syncthreads();
    for (int i = t; i < nn; i += 256) {
        int c = hist[i];
        cnt[nlo + i] = c;
        float deg = (float)c + 1.0f;
        dinv[nlo + i] = 1.0f / sqrtf(deg);
        snorm[nlo + i] = 1.0f / deg;
    }
}

// exclusive scan, 1024 elems per block
__global__ void scan1(const int* __restrict__ cnt, int* __restrict__ outp,
                      int* __restrict__ bsum, int n) {
    __shared__ int ls[256];
    int t = threadIdx.x;
    int base = blockIdx.x * 1024;
    int v[4], ex[4];
    int run = 0;
    #pragma unroll
    for (int j = 0; j < 4; ++j) {
        int i = base + t * 4 + j;
        v[j] = (i < n) ? cnt[i] : 0;
        ex[j] = run;
        run += v[j];
    }
    ls[t] = run;
    __syncthreads();
    for (int o2 = 1; o2 < 256; o2 <<= 1) {
        int xv = 0;
        if (t >= o2) xv = ls[t - o2];
        __syncthreads();
        ls[t] += xv;
        __syncthreads();
    }
    int tbase = ls[t] - run;   // exclusive base for this thread
    #pragma unroll
    for (int j = 0; j < 4; ++j) {
        int i = base + t * 4 + j;
        if (i < n) outp[i] = tbase + ex[j];
    }
    if (t == 255) bsum[blockIdx.x] = ls[255];
}

__global__ void scan2(int* __restrict__ bsum, int nb) {
    __shared__ int ls[256];
    int t = threadIdx.x;
    int v = (t < nb) ? bsum[t] : 0;
    ls[t] = v;
    __syncthreads();
    for (int o2 = 1; o2 < 256; o2 <<= 1) {
        int xv = 0;
        if (t >= o2) xv = ls[t - o2];
        __syncthreads();
        ls[t] += xv;
        __syncthreads();
    }
    if (t < nb) bsum[t] = ls[t] - v;     // exclusive
    if (t == 255) bsum[nb] = ls[255];    // total
}

__global__ void scan3(int* __restrict__ rowptr, const int* __restrict__ bsum, int n, int nb) {
    int i = blockIdx.x * blockDim.x + threadIdx.x;
    if (i < n) rowptr[i] += bsum[i >> 10];
    if (i == 0) rowptr[n] = bsum[nb];
}

__global__ void bin2(const int2* __restrict__ scratch, const int* __restrict__ rowptr,
                     int* __restrict__ fcur, int2* __restrict__ scratch2, int N, int E) {
    __shared__ int fcnt[NFMAX], fbase[NFMAX], foff[NFMAX];
    int t = threadIdx.x;
    int En = rowptr[N];
    int base = blockIdx.x * 8192;
    if (base >= En) return;
    int lim = En - base; if (lim > 8192) lim = 8192;
    for (int i = t; i < NFMAX; i += 256) { fcnt[i] = 0; foff[i] = 0; }
    __syncthreads();
    for (int i = t; i < lim; i += 256) {
        int d = scratch[base + i].y;
        atomicAdd(&fcnt[d >> FSHIFT], 1);
    }
    __syncthreads();
    for (int fi = t; fi < NFMAX; fi += 256) {
        if (fcnt[fi] > 0)
            fbase[fi] = rowptr[fi << FSHIFT] + atomicAdd(&fcur[fi], fcnt[fi]);
    }
    __syncthreads();
    for (int i = t; i < lim; i += 256) {
        int2 ed = scratch[base + i];
        int fi = ed.y >> FSHIFT;
        int pos = fbase[fi] + atomicAdd(&foff[fi], 1);
        scratch2[pos] = ed;
    }
}

__global__ __launch_bounds__(256) void scatter_sort(const int2* __restrict__ scratch2,
                                                    const int* __restrict__ rowptr,
                                                    const float* __restrict__ dinv,
                                                    int2* __restrict__ eprec, int N) {
    __shared__ int srcA[FCAP], dstA[FCAP], inv[FCAP];
    __shared__ int hist[1 << FSHIFT];
    __shared__ int hcur[1 << FSHIFT];
    int f = blockIdx.x, t = threadIdx.x;
    int nlo = f << FSHIFT;
    int nhi = nlo + (1 << FSHIFT); if (nhi > N) nhi = N;
    int lo = rowptr[nlo], hi = rowptr[nhi];
    int span = hi - lo;
    for (int i = t; i < (1 << FSHIFT); i += 256) hist[i] = 0;
    __syncthreads();
    if (span <= FCAP) {
        for (int i = t; i < span; i += 256) {
            int2 ed = scratch2[lo + i];
            srcA[i] = ed.x; dstA[i] = ed.y;
            atomicAdd(&hist[ed.y - nlo], 1);
        }
        __syncthreads();
        int v = hist[t];
        hcur[t] = v;
        __syncthreads();
        for (int o = 1; o < 256; o <<= 1) {
            int x = (t >= o) ? hcur[t - o] : 0;
            __syncthreads();
            hcur[t] += x;
            __syncthreads();
        }
        int excl = hcur[t] - v;
        __syncthreads();
        hcur[t] = excl;
        __syncthreads();
        for (int i = t; i < span; i += 256) {
            int slot = atomicAdd(&hcur[dstA[i] - nlo], 1);
            inv[slot] = i;
        }
        __syncthreads();
        for (int p = t; p < span; p += 256) {
            int i = inv[p];
            int s = srcA[i], d = dstA[i];
            eprec[lo + p] = make_int2(s, __float_as_int(dinv[s] * dinv[d]));
        }
    } else {
        for (int e = lo + t; e < hi; e += 256) {
            int2 ed = scratch2[e];
            int d = ed.y;
            int p = rowptr[d] + atomicAdd(&hist[d - nlo], 1);
            eprec[p] = make_int2(ed.x, __float_as_int(dinv[ed.x] * dinv[d]));
        }
    }
}

// ---------------- GEMMs (register-tiled: 4 cols/thread, b128 LDS reads) ----------------

__global__ void mm_128_32(const float* __restrict__ X, const float* __restrict__ W,
                          float* __restrict__ H, int n) {
    __shared__ float Ws[128 * 32];
    __shared__ float xs[32 * 128];
    int t = threadIdx.x;
    int rbase = blockIdx.x * 32;
    #pragma unroll
    for (int j = 0; j < 4; ++j) {
        int idx = t + 256 * j;           // float4 index, 1024 total
        *(float4*)(Ws + idx * 4) = *(const float4*)(W + idx * 4);
        int row = rbase + (idx >> 5);
        float4 v = make_float4(0.f, 0.f, 0.f, 0.f);
        if (row < n) v = *(const float4*)(X + (long)rbase * 128 + idx * 4);
        *(float4*)(xs + idx * 4) = v;
    }
    __syncthreads();
    int c4 = (t & 7) * 4, r = t >> 3;
    int row = rbase + r;
    if (row >= n) return;
    float ac0 = 0.f, ac1 = 0.f, ac2 = 0.f, ac3 = 0.f;
    #pragma unroll 8
    for (int k0 = 0; k0 < 128; k0 += 4) {
        float4 xv = *(const float4*)(xs + r * 128 + k0);
        #pragma unroll
        for (int j = 0; j < 4; ++j) {
            float xj = (j == 0) ? xv.x : (j == 1) ? xv.y : (j == 2) ? xv.z : xv.w;
            float4 wv = *(const float4*)(Ws + (k0 + j) * 32 + c4);
            ac0 += xj * wv.x; ac1 += xj * wv.y; ac2 += xj * wv.z; ac3 += xj * wv.w;
        }
    }
    *(float4*)(H + (long)row * 32 + c4) = make_float4(ac0, ac1, ac2, ac3);
}

__global__ void mm_32_32(const float* __restrict__ X, const float* __restrict__ W,
                         float* __restrict__ H, int n) {
    __shared__ float Ws[32 * 32];
    __shared__ float xs[32 * 32];
    int t = threadIdx.x;
    int rbase = blockIdx.x * 32;
    {
        *(float4*)(Ws + t * 4) = *(const float4*)(W + t * 4);
        int row = rbase + (t >> 3);
        float4 v = make_float4(0.f, 0.f, 0.f, 0.f);
        if (row < n) v = *(const float4*)(X + (long)rbase * 32 + t * 4);
        *(float4*)(xs + t * 4) = v;
    }
    __syncthreads();
    int c4 = (t & 7) * 4, r = t >> 3;
    int row = rbase + r;
    if (row >= n) return;
    float ac0 = 0.f, ac1 = 0.f, ac2 = 0.f, ac3 = 0.f;
    #pragma unroll
    for (int k0 = 0; k0 < 32; k0 += 4) {
        float4 xv = *(const float4*)(xs + r * 32 + k0);
        #pragma unroll
        for (int j = 0; j < 4; ++j) {
            float xj = (j == 0) ? xv.x : (j == 1) ? xv.y : (j == 2) ? xv.z : xv.w;
            float4 wv = *(const float4*)(Ws + (k0 + j) * 32 + c4);
            ac0 += xj * wv.x; ac1 += xj * wv.y; ac2 += xj * wv.z; ac3 += xj * wv.w;
        }
    }
    *(float4*)(H + (long)row * 32 + c4) = make_float4(ac0, ac1, ac2, ac3);
}

__global__ void mm_32_1(const float* __restrict__ X, const float* __restrict__ W,
                        float* __restrict__ H4, int n) {
    int gid = blockIdx.x * blockDim.x + threadIdx.x;
    int node = gid >> 3, l = gid & 7;
    if (node >= n) return;
    float4 v = *(const float4*)(X + (long)node * 32 + l * 4);
    float s = v.x * W[l * 4] + v.y * W[l * 4 + 1] + v.z * W[l * 4 + 2] + v.w * W[l * 4 + 3];
    s += __shfl_xor(s, 1, 64);
    s += __shfl_xor(s, 2, 64);
    s += __shfl_xor(s, 4, 64);
    if (l == 0) H4[node] = s;
}

// ---------------- edge aggregation (gather) ----------------

__global__ void agg32(const float* __restrict__ H, const int2* __restrict__ eprec,
                      const int* __restrict__ rowptr,
                      const float* __restrict__ snorm, const float* __restrict__ bias,
                      float* __restrict__ OUT, int n) {
    int gid = blockIdx.x * blockDim.x + threadIdx.x;
    int node = gid >> 3, l = gid & 7;
    if (node >= n) return;
    int beg = rowptr[node], end = rowptr[node + 1];
    float ax = 0.f, ay = 0.f, az = 0.f, aw = 0.f;
    int e0 = beg;
    for (; e0 + 8 <= end; e0 += 8) {
        int2 ed = eprec[e0 + l];
        int ss[8]; float ww[8];
        #pragma unroll
        for (int j = 0; j < 8; ++j) {
            ss[j] = __shfl(ed.x, j, 8);
            ww[j] = __shfl(__int_as_float(ed.y), j, 8);
        }
        float4 hv[8];
        #pragma unroll
        for (int j = 0; j < 8; ++j)
            hv[j] = *(const float4*)(H + (long)ss[j] * 32 + l * 4);
        #pragma unroll
        for (int j = 0; j < 8; ++j) {
            ax += hv[j].x * ww[j]; ay += hv[j].y * ww[j];
            az += hv[j].z * ww[j]; aw += hv[j].w * ww[j];
        }
    }
    if (e0 < end) {
        int m = end - e0;
        int2 ed = (l < m) ? eprec[e0 + l] : make_int2(0, 0);
        for (int j = 0; j < m; ++j) {
            int s = __shfl(ed.x, j, 8);
            float w = __shfl(__int_as_float(ed.y), j, 8);
            float4 hv = *(const float4*)(H + (long)s * 32 + l * 4);
            ax += hv.x * w; ay += hv.y * w; az += hv.z * w; aw += hv.w * w;
        }
    }
    float sn = snorm[node];
    float4 hv = *(const float4*)(H + (long)node * 32 + l * 4);
    float4 bv = *(const float4*)(bias + l * 4);
    float4 o;
    o.x = tanhf(ax + hv.x * sn + bv.x);
    o.y = tanhf(ay + hv.y * sn + bv.y);
    o.z = tanhf(az + hv.z * sn + bv.z);
    o.w = tanhf(aw + hv.w * sn + bv.w);
    *(float4*)(OUT + (long)node * 32 + l * 4) = o;
}

__global__ void agg1(const float* __restrict__ H4, const int2* __restrict__ eprec,
                     const int* __restrict__ rowptr,
                     const float* __restrict__ snorm, const float* __restrict__ b4,
                     float* __restrict__ X4, int n) {
    int node = blockIdx.x * blockDim.x + threadIdx.x;
    if (node >= n) return;
    int beg = rowptr[node], end = rowptr[node + 1];
    float acc = 0.f;
    for (int e = beg; e < end; ++e) {
        int2 ed = eprec[e];
        acc += H4[ed.x] * __int_as_float(ed.y);
    }
    X4[node] = tanhf(acc + H4[node] * snorm[node] + b4[0]);
}

// ---------------- topk per graph ----------------

__global__ void graph_start(const int* __restrict__ batch, int* __restrict__ gstart,
                            int n, int B) {
    int i = blockIdx.x * blockDim.x + threadIdx.x;
    if (i >= n) return;
    int b = batch[i];
    int bp = (i == 0) ? -1 : batch[i - 1];
    for (int g = bp + 1; g <= b; ++g) gstart[g] = i;
    if (i == n - 1) {
        for (int g = b + 1; g <= B; ++g) gstart[g] = n;
    }
}

// Fast path: whole candidate set in REGISTERS (32/lane x 64 lanes = 2048 cap).
// Per pass: 32 VALU compares + 6-shfl argmax + static-index mark. Identical
// selection order to the LDS version (lowest index wins ties).
__global__ __launch_bounds__(64) void topk_kernel(const float* __restrict__ keyf,
                                                  const int* __restrict__ gstart,
                                                  int* __restrict__ topi) {
    int g = blockIdx.x;
    int t = threadIdx.x;  // 0..63, single wave
    __shared__ float vals[TKCAP];
    __shared__ int selg[TOPK];
    int beg = gstart[g], end = gstart[g + 1];
    int range = end - beg;

    if (range <= 2048) {
        float rv[32];
        #pragma unroll
        for (int j = 0; j < 32; ++j) {
            int i = t + (j << 6);
            rv[j] = (i < range) ? keyf[beg + i] : -INFINITY;
        }
        for (int k = 0; k < TOPK; ++k) {
            float best = -INFINITY;
            int bj = -1;
            #pragma unroll
            for (int j = 0; j < 32; ++j)
                if (rv[j] > best) { best = rv[j]; bj = j; }
            int bi = (bj < 0) ? 0x7fffffff : (bj << 6) + t;
            #pragma unroll
            for (int off = 1; off < 64; off <<= 1) {
                float ov = __shfl_xor(best, off, 64);
                int oi = __shfl_xor(bi, off, 64);
                if (ov > best || (ov == best && oi < bi)) { best = ov; bi = oi; }
            }
            if (t == 0)
                topi[g * TOPK + k] = (bi == 0x7fffffff) ? -1 : beg + bi;
            if (bi != 0x7fffffff && (bi & 63) == t) {
                int wj = bi >> 6;
                #pragma unroll
                for (int j = 0; j < 32; ++j)
                    if (j == wj) rv[j] = -INFINITY;
            }
        }
        return;
    }

    // fallback: LDS-staged path (range > 2048; ~never at this problem size)
    int lim = range < TKCAP ? range : TKCAP;
    for (int i = t; i < lim; i += 64) vals[i] = keyf[beg + i];
    __syncthreads();
    for (int k = 0; k < TOPK; ++k) {
        float best = -INFINITY;
        int bi = 0x7fffffff;
        for (int i = t; i < lim; i += 64) {
            float v = vals[i];
            if (v > best) { best = v; bi = i; }
        }
        for (int i = TKCAP + t; i < range; i += 64) {
            int gi = beg + i;
            bool taken = false;
            for (int j = 0; j < k; ++j)
                if (selg[j] == gi) { taken = true; break; }
            if (taken) continue;
            float v = keyf[gi];
            if (v > best || (v == best && i < bi)) { best = v; bi = i; }
        }
        #pragma unroll
        for (int off = 1; off < 64; off <<= 1) {
            float ov = __shfl_xor(best, off, 64);
            int oi = __shfl_xor(bi, off, 64);
            if (ov > best || (ov == best && oi < bi)) { best = ov; bi = oi; }
        }
        if (t == 0) {
            int gl = (bi == 0x7fffffff) ? -1 : beg + bi;
            selg[k] = gl;
            topi[g * TOPK + k] = gl;
            if (bi != 0x7fffffff && bi < TKCAP) vals[bi] = -INFINITY;
        }
        __syncthreads();
    }
}

// ---------------- head: conv5 -> pool -> conv6 -> fc1 -> fc2 -> log_softmax ----------------

__global__ void head_kernel(const float* __restrict__ x1, const float* __restrict__ x2,
                            const float* __restrict__ x3, const float* __restrict__ x4,
                            const int* __restrict__ topi,
                            const float* __restrict__ w5, const float* __restrict__ b5,
                            const float* __restrict__ w6, const float* __restrict__ b6,
                            const float* __restrict__ fw1, const float* __restrict__ fb1,
                            const float* __restrict__ fw2, const float* __restrict__ fb2,
                            float* __restrict__ out) {
    int b = blockIdx.x;
    int t = threadIdx.x;
    __shared__ float feats[TOPK][97];
    __shared__ float c5[16][30];
    __shared__ float p6[16][15];
    __shared__ float z[352];
    __shared__ float hh[128];
    __shared__ float oo[10];

    for (int idx = t; idx < TOPK * 97; idx += 256) {
        int k = idx / 97, j = idx % 97;
        int node = topi[b * TOPK + k];
        float v = 0.f;
        if (node >= 0) {
            if (j < 32) v = x1[(long)node * 32 + j];
            else if (j < 64) v = x2[(long)node * 32 + (j - 32)];
            else if (j < 96) v = x3[(long)node * 32 + (j - 64)];
            else v = x4[node];
        }
        feats[k][j] = v;
    }
    __syncthreads();

    for (int idx = t; idx < 16 * 30; idx += 256) {
        int oc = idx / 30, k = idx % 30;
        float acc = b5[oc];
        for (int j = 0; j < 97; ++j) acc += w5[oc * 97 + j] * feats[k][j];
        c5[oc][k] = fmaxf(acc, 0.f);
    }
    __syncthreads();

    for (int idx = t; idx < 16 * 15; idx += 256) {
        int oc = idx / 15, k = idx % 15;
        p6[oc][k] = fmaxf(c5[oc][2 * k], c5[oc][2 * k + 1]);
    }
    __syncthreads();

    for (int idx = t; idx < 32 * 11; idx += 256) {
        int oc = idx / 11, tt = idx % 11;
        float acc = b6[oc];
        for (int ic = 0; ic < 16; ++ic)
            for (int j = 0; j < 5; ++j)
                acc += w6[(oc * 16 + ic) * 5 + j] * p6[ic][tt + j];
        z[idx] = fmaxf(acc, 0.f);
    }
    __syncthreads();

    if (t < 128) {
        float acc = fb1[t];
        for (int i = 0; i < 352; ++i) acc += z[i] * fw1[i * 128 + t];
        hh[t] = fmaxf(acc, 0.f);
    }
    __syncthreads();

    if (t < 10) {
        float acc = fb2[t];
        for (int j = 0; j < 128; ++j) acc += hh[j] * fw2[j * 10 + t];
        oo[t] = acc;
    }
    __syncthreads();

    if (t < 10) {
        float m = -INFINITY;
        for (int c = 0; c < 10; ++c) m = fmaxf(m, oo[c]);
        float s = 0.f;
        for (int c = 0; c < 10; ++c) s += expf(oo[c] - m);
        out[b * 10 + t] = oo[t] - m - logf(s);
    }
}

// ---------------- launch ----------------

extern "C" void kernel_launch(void* const* d_in, const int* in_sizes, int n_in,
                              void* d_out, int out_size, void* d_ws, size_t ws_size,
                              hipStream_t stream) {
    const float* x     = (const float*)d_in[0];
    const int*   ei    = (const int*)d_in[1];
    const int*   batch = (const int*)d_in[2];
    const float* W1 = (const float*)d_in[3];
    const float* b1 = (const float*)d_in[4];
    const float* W2 = (const float*)d_in[5];
    const float* b2 = (const float*)d_in[6];
    const float* W3 = (const float*)d_in[7];
    const float* b3 = (const float*)d_in[8];
    const float* W4 = (const float*)d_in[9];
    const float* b4 = (const float*)d_in[10];
    const float* w5 = (const float*)d_in[11];
    const float* b5 = (const float*)d_in[12];
    const float* w6 = (const float*)d_in[13];
    const float* b6 = (const float*)d_in[14];
    const float* fw1 = (const float*)d_in[15];
    const float* fb1 = (const float*)d_in[16];
    const float* fw2 = (const float*)d_in[17];
    const float* fb2 = (const float*)d_in[18];

    const int N = in_sizes[0] / 128;
    const int E = in_sizes[1] / 2;
    const int* src = ei;
    const int* dst = ei + E;

    char* w = (char*)d_ws;
    size_t off = 0;
    auto alloc = [&](size_t bytes) -> void* {
        void* p = w + off;
        off = (off + bytes + 255) & ~(size_t)255;
        return p;
    };

    int*   cnt    = (int*)alloc((size_t)N * 4);
    int*   rowptr = (int*)alloc((size_t)(N + 1) * 4);
    int*   bsum   = (int*)alloc(4096 * 4);
    int*   gcur   = (int*)alloc(NBMAX * 4);
    int*   btot   = (int*)alloc(NBMAX * 4);
    int*   bbase  = (int*)alloc(NBMAX * 4);
    int*   fcur   = (int*)alloc(NFMAX * 4);
    float* dinv   = (float*)alloc((size_t)N * 4);
    float* snorm  = (float*)alloc((size_t)N * 4);
    int2*  eprec  = (int2*)alloc((size_t)E * 8);
    float* hbuf   = (float*)alloc((size_t)N * 32 * 4);   // aliased as scratch
    float* x1     = (float*)alloc((size_t)N * 32 * 4);   // aliased as scratch2
    float* x2     = (float*)alloc((size_t)N * 32 * 4);
    float* x3     = (float*)alloc((size_t)N * 32 * 4);
    float* h4     = (float*)alloc((size_t)N * 4);
    float* x4     = (float*)alloc((size_t)N * 4);
    int*   gstart = (int*)alloc((size_t)(NGRAPH + 1) * 4);
    int*   topi   = (int*)alloc((size_t)NGRAPH * TOPK * 4);

    int2* scratch  = (int2*)hbuf;
    int2* scratch2 = (int2*)x1;

    hipMemsetAsync(gcur, 0, NBMAX * 4, stream);
    hipMemsetAsync(btot, 0, NBMAX * 4, stream);
    hipMemsetAsync(fcur, 0, NFMAX * 4, stream);

    const int NB = (N + (1 << BSHIFT) - 1) >> BSHIFT;
    const int NF = (N + (1 << FSHIFT) - 1) >> FSHIFT;
    const int EB = (E + 2047) / 2048;

    bhist<<<EB, TPB, 0, stream>>>(src, dst, btot, E);
    bucket_scan<<<1, NBMAX, 0, stream>>>(btot, bbase, NB);
    bin_edges<<<EB, TPB, 0, stream>>>(src, dst, bbase, gcur, scratch, E);
    bucket_count<<<NB, TPB, 0, stream>>>(scratch, bbase, btot, cnt, dinv, snorm, N);

    int nb = (N + 1023) / 1024;
    scan1<<<nb, 256, 0, stream>>>(cnt, rowptr, bsum, N);
    scan2<<<1, 256, 0, stream>>>(bsum, nb);
    scan3<<<(N + TPB - 1) / TPB, TPB, 0, stream>>>(rowptr, bsum, N, nb);

    bin2<<<(E + 8191) / 8192, TPB, 0, stream>>>(scratch, rowptr, fcur, scratch2, N, E);
    scatter_sort<<<NF, 256, 0, stream>>>(scratch2, rowptr, dinv, eprec, N);

    // layer 1
    mm_128_32<<<(N + 31) / 32, 256, 0, stream>>>(x, W1, hbuf, N);
    agg32<<<((size_t)N * 8 + TPB - 1) / TPB, TPB, 0, stream>>>(hbuf, eprec, rowptr,
                                                               snorm, b1, x1, N);
    // layer 2
    mm_32_32<<<(N + 31) / 32, 256, 0, stream>>>(x1, W2, hbuf, N);
    agg32<<<((size_t)N * 8 + TPB - 1) / TPB, TPB, 0, stream>>>(hbuf, eprec, rowptr,
                                                               snorm, b2, x2, N);
    // layer 3
    mm_32_32<<<(N + 31) / 32, 256, 0, stream>>>(x2, W3, hbuf, N);
    agg32<<<((size_t)N * 8 + TPB - 1) / TPB, TPB, 0, stream>>>(hbuf, eprec, rowptr,
                                                               snorm, b3, x3, N);
    // layer 4
    mm_32_1<<<((size_t)N * 8 + TPB - 1) / TPB, TPB, 0, stream>>>(x3, W4, h4, N);
    agg1<<<(N + TPB - 1) / TPB, TPB, 0, stream>>>(h4, eprec, rowptr, snorm, b4, x4, N);

    // topk + head
    graph_start<<<(N + TPB - 1) / TPB, TPB, 0, stream>>>(batch, gstart, N, NGRAPH);
    topk_kernel<<<NGRAPH, 64, 0, stream>>>(x4, gstart, topi);
    head_kernel<<<NGRAPH, 256, 0, stream>>>(x1, x2, x3, x4, topi, w5, b5, w6, b6,
                                            fw1, fb1, fw2, fb2, (float*)d_out);
}